// Round 1
// baseline (463.100 us; speedup 1.0000x reference)
//
#include <hip/hip_runtime.h>
#include <hip/hip_cooperative_groups.h>

namespace cg = cooperative_groups;

// Problem: B=64, L=512, D=768, S=8, HOP=3, LAMB=0.5
// Output depends only on sentence segments s in {5,6,7}.
// R5 change: fuse k0..k4 into ONE cooperative kernel (grid=256x256, 3 grid
// syncs) to kill inter-kernel launch/drain overhead (theory: ~25-35us device
// busy vs 224us measured => overhead-dominated).
//   - pooling writes 4 NON-atomic partial buffers sentP[q] (no zero needed)
//   - acc zeroing overlapped with pooling in stage 0
//   - GEMM x-staging sums the 4 partials (L2-resident)
//   - stage-2 K-split 128 (216 units) to fill the fused grid
// Fallback: original 5-kernel path if cooperative launch is rejected.

typedef unsigned short u16;
typedef short short8 __attribute__((ext_vector_type(8)));
typedef float f32x4 __attribute__((ext_vector_type(4)));

#define PSTRIDE 147456  // floats per pooling partial (64*2304)

__device__ __forceinline__ float bf2f(u16 h) {
    unsigned int u = ((unsigned int)h) << 16;
    float f;
    __builtin_memcpy(&f, &u, 4);
    return f;
}
__device__ __forceinline__ u16 f2bf(float f) {
    unsigned int u;
    __builtin_memcpy(&u, &f, 4);
    u = (u + 0x7fffu + ((u >> 16) & 1u)) >> 16;  // RNE
    return (u16)u;
}
__device__ __forceinline__ float sigm(float x) { return 1.0f / (1.0f + __expf(-x)); }

__device__ __forceinline__ float ldv(const void* p, long i, bool bf) {
    return bf ? bf2f(((const u16*)p)[i]) : ((const float*)p)[i];
}

// dtype detector: even-indexed u16s of fp32 N(0,1) data are mantissa bits
// (uniform -> ~6% in exponent window); of bf16 data they are values (~99%).
__device__ __forceinline__ bool detect_bf16(const u16* bert) {
    int hits = 0;
#pragma unroll
    for (int i = 0; i < 256; i += 2) {
        const int e = (bert[i] >> 7) & 0xFF;
        hits += (e >= 115 && e <= 130) ? 1 : 0;
    }
    return hits > 64;
}

// ---------------------------------------------------------------------------
// GEMM core: out(64 x Nout) += x(64 x K) @ B^T, 64x64 tile.
// K-chunk [k0, k0 + kiters*128).
// XMODE 0: x raw single fp32 array.
// XMODE 2: x = sum of 4 partial arrays at stride PSTRIDE (pooling partials).
// XMODE 1: x = tanh(raw + bias[k % 768]).
// WMODE 0: W is [k][n] row-major, n-dim 768. WMODE 1: conv weights (O,I,3).
// mfma_f32_16x16x32_bf16; C/D col=lane&15, row=quad*4+reg.
// ---------------------------------------------------------------------------
template <int XMODE, int WMODE>
__device__ __forceinline__ void gemm_core(
    const float* __restrict__ x, int xstride, const void* __restrict__ bias,
    const void* __restrict__ W, bool bf,
    float* __restrict__ out, int ostride,
    int n0, int k0, int kiters, u16* As, u16* Bs)
{
    const int t = threadIdx.x;
    const int r = t >> 2;             // 0..63
    const int cseg = (t & 3) * 32;    // 0,32,64,96
    const int wave = t >> 6, lane = t & 63;
    const int lm = lane & 15, lq = lane >> 4;
    f32x4 acc[4] = {};

    for (int kk = 0; kk < kiters * 128; kk += 128) {
        const int kg = k0 + kk;
        // ---- stage x -> As (fp32 -> bf16), row stride 136 ----
        {
            const float* xp = x + (size_t)r * xstride + (kg + cseg);
            u16* dst = As + r * 136 + cseg;
#pragma unroll
            for (int i = 0; i < 8; ++i) {
                float4 v = ((const float4*)xp)[i];
                if (XMODE == 2) {
                    float4 v1 = ((const float4*)(xp + PSTRIDE))[i];
                    float4 v2 = ((const float4*)(xp + 2 * PSTRIDE))[i];
                    float4 v3 = ((const float4*)(xp + 3 * PSTRIDE))[i];
                    v.x += v1.x + v2.x + v3.x;
                    v.y += v1.y + v2.y + v3.y;
                    v.z += v1.z + v2.z + v3.z;
                    v.w += v1.w + v2.w + v3.w;
                }
                if (XMODE == 1) {
                    int kb = kg + cseg + i * 4;
                    if (kb >= 768) kb -= 768;   // K <= 1536, 4-aligned
                    v.x = tanhf(v.x + ldv(bias, kb, bf));
                    v.y = tanhf(v.y + ldv(bias, kb + 1, bf));
                    v.z = tanhf(v.z + ldv(bias, kb + 2, bf));
                    v.w = tanhf(v.w + ldv(bias, kb + 3, bf));
                }
                ((ushort4*)dst)[i] = make_ushort4(f2bf(v.x), f2bf(v.y), f2bf(v.z), f2bf(v.w));
            }
        }
        // ---- stage W -> Bs as [n][k], row stride 136 ----
        if (WMODE == 0) {
            const int p = t >> 2;             // k-pair: k = 2p, 2p+1
            const int nseg = (t & 3) * 16;    // 16 n's
            u16 q0[16], q1[16];
            if (bf) {
                const u16* w0 = (const u16*)W + (size_t)(kg + 2 * p) * 768 + n0 + nseg;
                ((uint4*)q0)[0] = ((const uint4*)w0)[0];
                ((uint4*)q0)[1] = ((const uint4*)w0)[1];
                ((uint4*)q1)[0] = ((const uint4*)(w0 + 768))[0];
                ((uint4*)q1)[1] = ((const uint4*)(w0 + 768))[1];
            } else {
                const float* w0 = (const float*)W + (size_t)(kg + 2 * p) * 768 + n0 + nseg;
#pragma unroll
                for (int e = 0; e < 4; ++e) {
                    float4 v0 = ((const float4*)w0)[e];
                    float4 v1 = ((const float4*)(w0 + 768))[e];
                    q0[4 * e] = f2bf(v0.x); q0[4 * e + 1] = f2bf(v0.y);
                    q0[4 * e + 2] = f2bf(v0.z); q0[4 * e + 3] = f2bf(v0.w);
                    q1[4 * e] = f2bf(v1.x); q1[4 * e + 1] = f2bf(v1.y);
                    q1[4 * e + 2] = f2bf(v1.z); q1[4 * e + 3] = f2bf(v1.w);
                }
            }
#pragma unroll
            for (int e = 0; e < 16; ++e)
                *(ushort2*)(Bs + (nseg + e) * 136 + 2 * p) = make_ushort2(q0[e], q1[e]);
        } else {
            // conv: within a 128-chunk, kb = kg/768 is constant (768 = 6*128)
            const int kb = kg / 768;
            const int i0c = kg - kb * 768;
            u16 tmp[32];
            if (bf) {
                const u16* wp = (const u16*)W + (size_t)(n0 + r) * 2304 + (size_t)(i0c + cseg) * 3 + kb;
#pragma unroll
                for (int j = 0; j < 32; ++j) tmp[j] = wp[j * 3];
            } else {
                const float* wp = (const float*)W + (size_t)(n0 + r) * 2304 + (size_t)(i0c + cseg) * 3 + kb;
#pragma unroll
                for (int j = 0; j < 32; ++j) tmp[j] = f2bf(wp[j * 3]);
            }
            u16* dst = Bs + r * 136 + cseg;
#pragma unroll
            for (int qq = 0; qq < 8; ++qq)
                ((ushort4*)dst)[qq] = ((ushort4*)tmp)[qq];
        }
        __syncthreads();
        const u16* ap = As + (wave * 16 + lm) * 136 + lq * 8;
        const u16* bp = Bs + lm * 136 + lq * 8;
#pragma unroll
        for (int ks = 0; ks < 4; ++ks) {
            short8 af = *(const short8*)(ap + ks * 32);
#pragma unroll
            for (int nf = 0; nf < 4; ++nf) {
                short8 bfr = *(const short8*)(bp + nf * 16 * 136 + ks * 32);
                acc[nf] = __builtin_amdgcn_mfma_f32_16x16x32_bf16(af, bfr, acc[nf], 0, 0, 0);
            }
        }
        __syncthreads();
    }
#pragma unroll
    for (int nf = 0; nf < 4; ++nf) {
#pragma unroll
        for (int rg = 0; rg < 4; ++rg) {
            const int row = wave * 16 + lq * 4 + rg;
            const int col = n0 + nf * 16 + lm;
            atomicAdd(out + (size_t)row * ostride + col, acc[nf][rg]);
        }
    }
}

__device__ __forceinline__ float block_sum(float v, float* red) {
#pragma unroll
    for (int m = 1; m < 64; m <<= 1) v += __shfl_xor(v, m, 64);
    const int wave = threadIdx.x >> 6, lane = threadIdx.x & 63;
    if (lane == 0) red[wave] = v;
    __syncthreads();
    const float r = red[0] + red[1] + red[2] + red[3];
    __syncthreads();
    return r;
}

// ---------------------------------------------------------------------------
// Fused cooperative kernel: grid = 256 blocks x 256 threads (co-resident).
// stage0: pooling partials + zero accs | sync | stage1: GEMM-A | sync |
// stage2: GEMM-B | sync | stage3: refine chains + softmax + fc2
// ---------------------------------------------------------------------------
__global__ __launch_bounds__(256) void kfused(
    const void* __restrict__ bert, const int* __restrict__ sb,
    const void* __restrict__ target,
    const void* __restrict__ gc1w, const void* __restrict__ gc1b,
    const void* __restrict__ gc2w, const void* __restrict__ gc2b,
    const void* __restrict__ c1w, const void* __restrict__ c1b,
    const void* __restrict__ c2w, const void* __restrict__ c2b,
    const void* __restrict__ lng, const void* __restrict__ lnb,
    const void* __restrict__ fc2w, const void* __restrict__ fc2b,
    void* __restrict__ outp, float* __restrict__ ws)
{
    __shared__ u16 As[64 * 136];
    __shared__ u16 Bs[64 * 136];
    __shared__ float red[4];
    const int t = threadIdx.x;
    const int blk = blockIdx.x;
    cg::grid_group grid = cg::this_grid();

    const bool bf = detect_bf16((const u16*)bert);
    const bool is64 = (sb[1] == 0);

    float* sentP = ws;                      // 4 x 147456 floats (partials)
    float* accs  = ws + 4 * PSTRIDE;        // 245760 floats
    float* g1acc = accs;                    // 64 x 768
    float* c1acc = g1acc + 49152;           // 64 x 1536 [c1_6 | c1_7]
    float* g2acc = c1acc + 98304;           // 64 x 768
    float* c2acc = g2acc + 49152;           // 64 x 768

    // ---- stage 0a: zero GEMM accumulators (245760 f = 61440 float4) ----
    if (t < 240)
        ((float4*)accs)[blk * 240 + t] = make_float4(0.f, 0.f, 0.f, 0.f);

    // ---- stage 0b: segment mean pooling -> 4 non-atomic partials ----
#pragma unroll
    for (int un = 0; un < 3; ++un) {
        const int u = blk + 256 * un;          // 0..767
        const int q = u & 3, v = u >> 2;       // v in [0,192)
        const int b = v / 3, si = v - 3 * (v / 3), s = 5 + si;
        const int i0 = b * 9 + s, i1 = i0 + 1;
        int st = is64 ? sb[2 * i0] : sb[i0];
        int en = is64 ? sb[2 * i1] : sb[i1];
        st = st < 0 ? 0 : (st > 511 ? 511 : st);
        en = en <= st ? st + 1 : (en > 512 ? 512 : en);
        const int n = en - st;
        const int r0 = st + (n * q) / 4;
        const int r1 = st + (n * (q + 1)) / 4;
        float a0 = 0.f, a1 = 0.f, a2 = 0.f;
        if (bf) {
            const u16* base = (const u16*)bert + (size_t)b * 512 * 768;
            int l = r0;
            for (; l + 1 < r1; l += 2) {
                const u16* p0 = base + (size_t)l * 768;
                const u16* p1 = p0 + 768;
                a0 += bf2f(p0[t]) + bf2f(p1[t]);
                a1 += bf2f(p0[t + 256]) + bf2f(p1[t + 256]);
                a2 += bf2f(p0[t + 512]) + bf2f(p1[t + 512]);
            }
            if (l < r1) {
                const u16* p0 = base + (size_t)l * 768;
                a0 += bf2f(p0[t]);
                a1 += bf2f(p0[t + 256]);
                a2 += bf2f(p0[t + 512]);
            }
        } else {
            const float* base = (const float*)bert + (size_t)b * 512 * 768;
            int l = r0;
            for (; l + 1 < r1; l += 2) {
                const float* p0 = base + (size_t)l * 768;
                const float* p1 = p0 + 768;
                a0 += p0[t] + p1[t];
                a1 += p0[t + 256] + p1[t + 256];
                a2 += p0[t + 512] + p1[t + 512];
            }
            if (l < r1) {
                const float* p0 = base + (size_t)l * 768;
                a0 += p0[t];
                a1 += p0[t + 256];
                a2 += p0[t + 512];
            }
        }
        const float inv = 1.0f / (float)n;
        float* o = sentP + (size_t)q * PSTRIDE + b * 2304 + si * 768;
        o[t] = a0 * inv;
        o[t + 256] = a1 * inv;
        o[t + 512] = a2 * inv;
    }

    __threadfence();
    grid.sync();
    __threadfence();

    // ---- stage 1: GEMM-A (216 units, K-chunks of 256) ----
    if (blk < 216) {
        const int u = blk;
        if (u < 36) {
            gemm_core<2, 0>(sentP + 1536, 2304, nullptr, gc1w, bf, g1acc, 768,
                            (u / 3) * 64, (u % 3) * 256, 2, As, Bs);
        } else if (u < 144) {
            const int v = u - 36;
            gemm_core<2, 1>(sentP, 2304, nullptr, c1w, bf, c1acc, 1536,
                            (v / 9) * 64, (v % 9) * 256, 2, As, Bs);
        } else {
            const int v = u - 144;
            gemm_core<2, 1>(sentP + 768, 2304, nullptr, c1w, bf, c1acc + 768, 1536,
                            (v / 6) * 64, (v % 6) * 256, 2, As, Bs);
        }
    }

    __threadfence();
    grid.sync();
    __threadfence();

    // ---- stage 2: GEMM-B (216 units, K-chunks of 128) ----
    if (blk < 216) {
        const int u = blk;
        if (u < 72) {
            gemm_core<1, 0>(g1acc, 768, gc1b, gc2w, bf, g2acc, 768,
                            (u / 6) * 64, (u % 6) * 128, 1, As, Bs);
        } else {
            const int v = u - 72;
            gemm_core<1, 1>(c1acc, 1536, c1b, c2w, bf, c2acc, 768,
                            (v / 12) * 64, (v % 12) * 128, 1, As, Bs);
        }
    }

    __threadfence();
    grid.sync();
    __threadfence();

    // ---- stage 3: per-batch refine chains + softmax + fc2 (64 units) ----
    if (blk < 64) {
        const int b = blk;
        float s_[3], g_[3], bb_[3];
        const float* srow = sentP + b * 2304 + 1536;  // sent7 partial q=0
#pragma unroll
        for (int i = 0; i < 3; ++i) {
            const int d = t + 256 * i;
            s_[i] = srow[d] + srow[d + PSTRIDE] + srow[d + 2 * PSTRIDE] + srow[d + 3 * PSTRIDE];
            g_[i] = ldv(lng, d, bf);
            bb_[i] = ldv(lnb, d, bf);
        }

        auto refine2 = [&](float* yv) {
#pragma unroll
            for (int it = 0; it < 2; ++it) {
                const float c = block_sum(yv[0] * s_[0] + yv[1] * s_[1] + yv[2] * s_[2], red);
                float tt[3], sm = 0.0f, sq = 0.0f;
#pragma unroll
                for (int i = 0; i < 3; ++i) {
                    tt[i] = sigm(c * s_[i]);
                    sm += tt[i];
                    sq += tt[i] * tt[i];
                }
                const float m = block_sum(sm, red) * (1.0f / 768.0f);
                const float q = block_sum(sq, red) * (1.0f / 768.0f);
                const float inv = rsqrtf(fmaxf(q - m * m, 0.0f) + 1e-5f);
#pragma unroll
                for (int i = 0; i < 3; ++i)
                    yv[i] = 0.5f * ((tt[i] - m) * inv * g_[i] + bb_[i]) + s_[i];
            }
        };

        float a3[3], a4[3], a5[3], y[3];
#pragma unroll
        for (int i = 0; i < 3; ++i) {
            const int d = t + 256 * i;
            y[i] = tanhf(g2acc[b * 768 + d] + ldv(gc2b, d, bf));
        }
        refine2(y);
        a3[0] = y[0]; a3[1] = y[1]; a3[2] = y[2];
#pragma unroll
        for (int i = 0; i < 3; ++i) {
            const int d = t + 256 * i;
            y[i] = tanhf(c2acc[b * 768 + d] + ldv(c2b, d, bf));
        }
        refine2(y);
        a4[0] = y[0]; a4[1] = y[1]; a4[2] = y[2];
        const float ss = block_sum(s_[0] * s_[0] + s_[1] * s_[1] + s_[2] * s_[2], red);
#pragma unroll
        for (int i = 0; i < 3; ++i) y[i] = sigm(ss * s_[i]);
        refine2(y);
        a5[0] = y[0]; a5[1] = y[1]; a5[2] = y[2];

        float tg[3];
#pragma unroll
        for (int i = 0; i < 3; ++i) tg[i] = ldv(target, t + 256 * i, bf);  // target[0]
        const float u0 = block_sum(a3[0] * tg[0] + a3[1] * tg[1] + a3[2] * tg[2], red);
        const float u1 = block_sum(a4[0] * tg[0] + a4[1] * tg[1] + a4[2] * tg[2], red);
        const float u2 = block_sum(a5[0] * tg[0] + a5[1] * tg[1] + a5[2] * tg[2], red);
        const float mx = fmaxf(u0, fmaxf(u1, u2));
        const float e0 = __expf(u0 - mx), e1 = __expf(u1 - mx), e2 = __expf(u2 - mx);
        const float es = e0 + e1 + e2;
        const float w0 = e0 / es, w1 = e1 / es, w2 = e2 / es;

        float p0 = 0.0f, p1 = 0.0f, p2 = 0.0f;
#pragma unroll
        for (int i = 0; i < 3; ++i) {
            const int d = t + 256 * i;
            const float va = w0 * a3[i], vb = w1 * a4[i], vc = w2 * a5[i];
            p0 += va * ldv(fc2w, d * 3 + 0, bf) + vb * ldv(fc2w, (768 + d) * 3 + 0, bf) + vc * ldv(fc2w, (1536 + d) * 3 + 0, bf);
            p1 += va * ldv(fc2w, d * 3 + 1, bf) + vb * ldv(fc2w, (768 + d) * 3 + 1, bf) + vc * ldv(fc2w, (1536 + d) * 3 + 1, bf);
            p2 += va * ldv(fc2w, d * 3 + 2, bf) + vb * ldv(fc2w, (768 + d) * 3 + 2, bf) + vc * ldv(fc2w, (1536 + d) * 3 + 2, bf);
        }
        p0 = block_sum(p0, red);
        p1 = block_sum(p1, red);
        p2 = block_sum(p2, red);
        if (t == 0) {
            const float o0 = p0 + ldv(fc2b, 0, bf);
            const float o1 = p1 + ldv(fc2b, 1, bf);
            const float o2 = p2 + ldv(fc2b, 2, bf);
            if (bf) {
                ((u16*)outp)[b * 3 + 0] = f2bf(o0);
                ((u16*)outp)[b * 3 + 1] = f2bf(o1);
                ((u16*)outp)[b * 3 + 2] = f2bf(o2);
            } else {
                ((float*)outp)[b * 3 + 0] = o0;
                ((float*)outp)[b * 3 + 1] = o1;
                ((float*)outp)[b * 3 + 2] = o2;
            }
        }
    }
}

// ===========================================================================
// Fallback path: original 5-kernel pipeline (used only if cooperative launch
// is rejected, e.g. unsupported under graph capture).
// ===========================================================================
__global__ __launch_bounds__(256) void k0_zero(float* __restrict__ ws)
{
    ((float4*)ws)[blockIdx.x * 256 + threadIdx.x] = make_float4(0.f, 0.f, 0.f, 0.f);
}

__global__ __launch_bounds__(256) void k1_pool(
    const void* __restrict__ bertv, const int* __restrict__ sb,
    float* __restrict__ sentF, float* __restrict__ flagp)
{
    const int u = blockIdx.x, t = threadIdx.x;
    const bool bf = detect_bf16((const u16*)bertv);
    const bool is64 = (sb[1] == 0);
    if (u == 0 && t == 0) flagp[0] = bf ? 1.0f : 0.0f;
    const int q = u & 3, v = u >> 2;
    const int b = v / 3, si = v - 3 * (v / 3), s = 5 + si;
    const int i0 = b * 9 + s, i1 = i0 + 1;
    int st = is64 ? sb[2 * i0] : sb[i0];
    int en = is64 ? sb[2 * i1] : sb[i1];
    st = st < 0 ? 0 : (st > 511 ? 511 : st);
    en = en <= st ? st + 1 : (en > 512 ? 512 : en);
    const int n = en - st;
    const int r0 = st + (n * q) / 4;
    const int r1 = st + (n * (q + 1)) / 4;
    float a0 = 0.f, a1 = 0.f, a2 = 0.f;
    if (bf) {
        const u16* base = (const u16*)bertv + (size_t)b * 512 * 768;
        int l = r0;
        for (; l + 1 < r1; l += 2) {
            const u16* p0 = base + (size_t)l * 768;
            const u16* p1 = p0 + 768;
            a0 += bf2f(p0[t]) + bf2f(p1[t]);
            a1 += bf2f(p0[t + 256]) + bf2f(p1[t + 256]);
            a2 += bf2f(p0[t + 512]) + bf2f(p1[t + 512]);
        }
        if (l < r1) {
            const u16* p0 = base + (size_t)l * 768;
            a0 += bf2f(p0[t]); a1 += bf2f(p0[t + 256]); a2 += bf2f(p0[t + 512]);
        }
    } else {
        const float* base = (const float*)bertv + (size_t)b * 512 * 768;
        int l = r0;
        for (; l + 1 < r1; l += 2) {
            const float* p0 = base + (size_t)l * 768;
            const float* p1 = p0 + 768;
            a0 += p0[t] + p1[t];
            a1 += p0[t + 256] + p1[t + 256];
            a2 += p0[t + 512] + p1[t + 512];
        }
        if (l < r1) {
            const float* p0 = base + (size_t)l * 768;
            a0 += p0[t]; a1 += p0[t + 256]; a2 += p0[t + 512];
        }
    }
    const float inv = 1.0f / (float)n;
    float* o = sentF + b * 2304 + si * 768;
    atomicAdd(o + t, a0 * inv);
    atomicAdd(o + t + 256, a1 * inv);
    atomicAdd(o + t + 512, a2 * inv);
}

__global__ __launch_bounds__(256) void k2_gemm_a(
    const float* __restrict__ sentF, const void* __restrict__ gc1w,
    const void* __restrict__ c1w, float* __restrict__ g1acc, float* __restrict__ c1acc,
    const float* __restrict__ flagp)
{
    __shared__ u16 As[64 * 136];
    __shared__ u16 Bs[64 * 136];
    const bool bf = flagp[0] > 0.5f;
    const int u = blockIdx.x;
    if (u < 36) {
        gemm_core<0, 0>(sentF + 1536, 2304, nullptr, gc1w, bf, g1acc, 768,
                        (u / 3) * 64, (u % 3) * 256, 2, As, Bs);
    } else if (u < 144) {
        const int v = u - 36;
        gemm_core<0, 1>(sentF, 2304, nullptr, c1w, bf, c1acc, 1536,
                        (v / 9) * 64, (v % 9) * 256, 2, As, Bs);
    } else {
        const int v = u - 144;
        gemm_core<0, 1>(sentF + 768, 2304, nullptr, c1w, bf, c1acc + 768, 1536,
                        (v / 6) * 64, (v % 6) * 256, 2, As, Bs);
    }
}

__global__ __launch_bounds__(256) void k3_gemm_b(
    const float* __restrict__ g1acc, const float* __restrict__ c1acc,
    const void* __restrict__ gc2w, const void* __restrict__ c2w,
    const void* __restrict__ gc1b, const void* __restrict__ c1b,
    float* __restrict__ g2acc, float* __restrict__ c2acc,
    const float* __restrict__ flagp)
{
    __shared__ u16 As[64 * 136];
    __shared__ u16 Bs[64 * 136];
    const bool bf = flagp[0] > 0.5f;
    const int u = blockIdx.x;
    if (u < 36) {
        gemm_core<1, 0>(g1acc, 768, gc1b, gc2w, bf, g2acc, 768,
                        (u / 3) * 64, (u % 3) * 256, 2, As, Bs);
    } else {
        const int v = u - 36;
        gemm_core<1, 1>(c1acc, 1536, c1b, c2w, bf, c2acc, 768,
                        (v / 6) * 64, (v % 6) * 256, 2, As, Bs);
    }
}

__global__ __launch_bounds__(256) void k4_final(
    const float* __restrict__ sentF, const float* __restrict__ g2acc,
    const float* __restrict__ c2acc,
    const void* __restrict__ gc2b, const void* __restrict__ c2b,
    const void* __restrict__ lng, const void* __restrict__ lnb,
    const void* __restrict__ target, const void* __restrict__ fc2w,
    const void* __restrict__ fc2b, void* __restrict__ outp,
    const float* __restrict__ flagp)
{
    __shared__ float red[4];
    const bool bf = flagp[0] > 0.5f;
    const int t = threadIdx.x, b = blockIdx.x;
    float s_[3], g_[3], bb_[3];
    const float* srow = sentF + b * 2304 + 1536;
#pragma unroll
    for (int i = 0; i < 3; ++i) {
        const int d = t + 256 * i;
        s_[i] = srow[d];
        g_[i] = ldv(lng, d, bf);
        bb_[i] = ldv(lnb, d, bf);
    }
    auto refine2 = [&](float* yv) {
#pragma unroll
        for (int it = 0; it < 2; ++it) {
            const float c = block_sum(yv[0] * s_[0] + yv[1] * s_[1] + yv[2] * s_[2], red);
            float tt[3], sm = 0.0f, sq = 0.0f;
#pragma unroll
            for (int i = 0; i < 3; ++i) {
                tt[i] = sigm(c * s_[i]);
                sm += tt[i];
                sq += tt[i] * tt[i];
            }
            const float m = block_sum(sm, red) * (1.0f / 768.0f);
            const float q = block_sum(sq, red) * (1.0f / 768.0f);
            const float inv = rsqrtf(fmaxf(q - m * m, 0.0f) + 1e-5f);
#pragma unroll
            for (int i = 0; i < 3; ++i)
                yv[i] = 0.5f * ((tt[i] - m) * inv * g_[i] + bb_[i]) + s_[i];
        }
    };
    float a3[3], a4[3], a5[3], y[3];
#pragma unroll
    for (int i = 0; i < 3; ++i) {
        const int d = t + 256 * i;
        y[i] = tanhf(g2acc[b * 768 + d] + ldv(gc2b, d, bf));
    }
    refine2(y);
    a3[0] = y[0]; a3[1] = y[1]; a3[2] = y[2];
#pragma unroll
    for (int i = 0; i < 3; ++i) {
        const int d = t + 256 * i;
        y[i] = tanhf(c2acc[b * 768 + d] + ldv(c2b, d, bf));
    }
    refine2(y);
    a4[0] = y[0]; a4[1] = y[1]; a4[2] = y[2];
    const float ss = block_sum(s_[0] * s_[0] + s_[1] * s_[1] + s_[2] * s_[2], red);
#pragma unroll
    for (int i = 0; i < 3; ++i) y[i] = sigm(ss * s_[i]);
    refine2(y);
    a5[0] = y[0]; a5[1] = y[1]; a5[2] = y[2];
    float tg[3];
#pragma unroll
    for (int i = 0; i < 3; ++i) tg[i] = ldv(target, t + 256 * i, bf);
    const float u0 = block_sum(a3[0] * tg[0] + a3[1] * tg[1] + a3[2] * tg[2], red);
    const float u1 = block_sum(a4[0] * tg[0] + a4[1] * tg[1] + a4[2] * tg[2], red);
    const float u2 = block_sum(a5[0] * tg[0] + a5[1] * tg[1] + a5[2] * tg[2], red);
    const float mx = fmaxf(u0, fmaxf(u1, u2));
    const float e0 = __expf(u0 - mx), e1 = __expf(u1 - mx), e2 = __expf(u2 - mx);
    const float es = e0 + e1 + e2;
    const float w0 = e0 / es, w1 = e1 / es, w2 = e2 / es;
    float p0 = 0.0f, p1 = 0.0f, p2 = 0.0f;
#pragma unroll
    for (int i = 0; i < 3; ++i) {
        const int d = t + 256 * i;
        const float va = w0 * a3[i], vb = w1 * a4[i], vc = w2 * a5[i];
        p0 += va * ldv(fc2w, d * 3 + 0, bf) + vb * ldv(fc2w, (768 + d) * 3 + 0, bf) + vc * ldv(fc2w, (1536 + d) * 3 + 0, bf);
        p1 += va * ldv(fc2w, d * 3 + 1, bf) + vb * ldv(fc2w, (768 + d) * 3 + 1, bf) + vc * ldv(fc2w, (1536 + d) * 3 + 1, bf);
        p2 += va * ldv(fc2w, d * 3 + 2, bf) + vb * ldv(fc2w, (768 + d) * 3 + 2, bf) + vc * ldv(fc2w, (1536 + d) * 3 + 2, bf);
    }
    p0 = block_sum(p0, red);
    p1 = block_sum(p1, red);
    p2 = block_sum(p2, red);
    if (t == 0) {
        const float o0 = p0 + ldv(fc2b, 0, bf);
        const float o1 = p1 + ldv(fc2b, 1, bf);
        const float o2 = p2 + ldv(fc2b, 2, bf);
        if (bf) {
            ((u16*)outp)[b * 3 + 0] = f2bf(o0);
            ((u16*)outp)[b * 3 + 1] = f2bf(o1);
            ((u16*)outp)[b * 3 + 2] = f2bf(o2);
        } else {
            ((float*)outp)[b * 3 + 0] = o0;
            ((float*)outp)[b * 3 + 1] = o1;
            ((float*)outp)[b * 3 + 2] = o2;
        }
    }
}

extern "C" void kernel_launch(void* const* d_in, const int* in_sizes, int n_in,
                              void* d_out, int out_size, void* d_ws, size_t ws_size,
                              hipStream_t stream) {
    const void* bert   = d_in[0];
    const void* target = d_in[1];
    const void* gc1w   = d_in[2];
    const void* gc1b   = d_in[3];
    const void* gc2w   = d_in[4];
    const void* gc2b   = d_in[5];
    const void* c1w    = d_in[6];
    const void* c1b    = d_in[7];
    const void* c2w    = d_in[8];
    const void* c2b    = d_in[9];
    const void* lng    = d_in[10];
    const void* lnb    = d_in[11];
    const void* fc2w   = d_in[12];
    const void* fc2b   = d_in[13];
    const int*  sb     = (const int*)d_in[14];
    float* wsf = (float*)d_ws;

    void* args[17] = {
        (void*)&bert, (void*)&sb, (void*)&target,
        (void*)&gc1w, (void*)&gc1b, (void*)&gc2w, (void*)&gc2b,
        (void*)&c1w, (void*)&c1b, (void*)&c2w, (void*)&c2b,
        (void*)&lng, (void*)&lnb, (void*)&fc2w, (void*)&fc2b,
        (void*)&d_out, (void*)&wsf};
    hipError_t err = hipLaunchCooperativeKernel(
        (void*)kfused, dim3(256), dim3(256), args, 0, stream);

    if (err != hipSuccess) {
        // Fallback: original 5-kernel pipeline (distinct ws layout).
        float* sentF = wsf;                // 147456 floats
        float* accs  = sentF + 147456;     // 245760 floats
        float* g1acc = accs;
        float* c1acc = accs + 49152;
        float* g2acc = c1acc + 98304;
        float* c2acc = g2acc + 49152;
        float* flagp = accs + 245760;
        k0_zero<<<384, 256, 0, stream>>>(sentF);
        k1_pool<<<768, 256, 0, stream>>>(bert, sb, sentF, flagp);
        k2_gemm_a<<<216, 256, 0, stream>>>(sentF, gc1w, c1w, g1acc, c1acc, flagp);
        k3_gemm_b<<<108, 256, 0, stream>>>(g1acc, c1acc, gc2w, c2w, gc1b, c1b, g2acc, c2acc, flagp);
        k4_final<<<64, 256, 0, stream>>>(sentF, g2acc, c2acc, gc2b, c2b, lng, lnb,
                                         target, fc2w, fc2b, d_out, flagp);
    }
}

// Round 2
// 295.997 us; speedup vs baseline: 1.5645x; 1.5645x over previous
//
#include <hip/hip_runtime.h>

// Problem: B=64, L=512, D=768, S=8, HOP=3, LAMB=0.5
// Output depends only on sentence segments s in {5,6,7}.
// R6: single NON-cooperative kernel, grid=768x256 (3 blocks/CU, structurally
// all-resident: 35KB LDS -> <=4 blocks/CU, 768 <= 256CU*4). Cross-stage sync
// via hand-rolled fence-free barrier:
//   - ALL cross-stage writes are device-scope atomicAdd (coherent at IF$,
//     no dirty L2 lines -> no buffer_wbl2 needed)
//   - readers use plain loads (L2s clean at dispatch start; no block touches
//     an acc line before its producer stage -> no stale copies possible)
//   - barrier: s_waitcnt vmcnt(0) + relaxed agent fetch_add + relaxed agent
//     spin load + s_sleep. ZERO fences (R5's cg::sync / __threadfence did
//     per-wave full-L2 writeback-invalidates -> 330us of stall).
// sentF + accs + barrier counters zeroed by ONE hipMemsetAsync (1.5 MB).

typedef unsigned short u16;
typedef short short8 __attribute__((ext_vector_type(8)));
typedef float f32x4 __attribute__((ext_vector_type(4)));

#define NBLK 768

__device__ __forceinline__ float bf2f(u16 h) {
    unsigned int u = ((unsigned int)h) << 16;
    float f;
    __builtin_memcpy(&f, &u, 4);
    return f;
}
__device__ __forceinline__ u16 f2bf(float f) {
    unsigned int u;
    __builtin_memcpy(&u, &f, 4);
    u = (u + 0x7fffu + ((u >> 16) & 1u)) >> 16;  // RNE
    return (u16)u;
}
__device__ __forceinline__ float sigm(float x) { return 1.0f / (1.0f + __expf(-x)); }

__device__ __forceinline__ float ldv(const void* p, long i, bool bf) {
    return bf ? bf2f(((const u16*)p)[i]) : ((const float*)p)[i];
}

// dtype detector: even-indexed u16s of fp32 N(0,1) data are mantissa bits
// (uniform -> ~6% in exponent window); of bf16 data they are values (~99%).
__device__ __forceinline__ bool detect_bf16(const u16* bert) {
    int hits = 0;
#pragma unroll
    for (int i = 0; i < 256; i += 2) {
        const int e = (bert[i] >> 7) & 0xFF;
        hits += (e >= 115 && e <= 130) ? 1 : 0;
    }
    return hits > 64;
}

// Fence-free device-wide barrier. Requirements satisfied by construction:
// all cross-stage data writes are device-scope atomics (at coherence point
// when vmcnt hits 0); counter ops are agent-scope relaxed atomics (bypass
// L1/L2); readers' plain loads miss clean L2s and fill from the coherence
// point.
__device__ __forceinline__ void gbar(unsigned* cnt, unsigned target) {
    __syncthreads();
    if (threadIdx.x == 0) {
        asm volatile("s_waitcnt vmcnt(0)" ::: "memory");
        __hip_atomic_fetch_add(cnt, 1u, __ATOMIC_RELAXED, __HIP_MEMORY_SCOPE_AGENT);
        int polls = 0;
        while (__hip_atomic_load(cnt, __ATOMIC_RELAXED, __HIP_MEMORY_SCOPE_AGENT) < target) {
            __builtin_amdgcn_s_sleep(2);
            if (++polls > (1 << 22)) break;  // deadlock bail: wrong answer > hang
        }
    }
    __syncthreads();
}

// ---------------------------------------------------------------------------
// GEMM core: out(64 x Nout) += x(64 x K) @ B^T, 64x64 tile.
// K-chunk [k0, k0 + kiters*128). x always fp32 (workspace), plain loads.
// XMODE 0: x raw. XMODE 1: x = tanh(raw + bias[k % 768]).
// WMODE 0: W is [k][n] row-major, n-dim 768. WMODE 1: conv weights (O,I,3).
// mfma_f32_16x16x32_bf16; C/D col=lane&15, row=quad*4+reg. Output atomicAdd.
// ---------------------------------------------------------------------------
template <int XMODE, int WMODE>
__device__ __forceinline__ void gemm_core(
    const float* __restrict__ x, int xstride, const void* __restrict__ bias,
    const void* __restrict__ W, bool bf,
    float* __restrict__ out, int ostride,
    int n0, int k0, int kiters, u16* As, u16* Bs)
{
    const int t = threadIdx.x;
    const int r = t >> 2;             // 0..63
    const int cseg = (t & 3) * 32;    // 0,32,64,96
    const int wave = t >> 6, lane = t & 63;
    const int lm = lane & 15, lq = lane >> 4;
    f32x4 acc[4] = {};

    for (int kk = 0; kk < kiters * 128; kk += 128) {
        const int kg = k0 + kk;
        // ---- stage x -> As (fp32 -> bf16), row stride 136 ----
        {
            const float* xp = x + (size_t)r * xstride + (kg + cseg);
            u16* dst = As + r * 136 + cseg;
#pragma unroll
            for (int i = 0; i < 8; ++i) {
                float4 v = ((const float4*)xp)[i];
                if (XMODE == 1) {
                    int kb = kg + cseg + i * 4;
                    if (kb >= 768) kb -= 768;   // K <= 1536, 4-aligned
                    v.x = tanhf(v.x + ldv(bias, kb, bf));
                    v.y = tanhf(v.y + ldv(bias, kb + 1, bf));
                    v.z = tanhf(v.z + ldv(bias, kb + 2, bf));
                    v.w = tanhf(v.w + ldv(bias, kb + 3, bf));
                }
                ((ushort4*)dst)[i] = make_ushort4(f2bf(v.x), f2bf(v.y), f2bf(v.z), f2bf(v.w));
            }
        }
        // ---- stage W -> Bs as [n][k], row stride 136 ----
        if (WMODE == 0) {
            const int p = t >> 2;             // k-pair: k = 2p, 2p+1
            const int nseg = (t & 3) * 16;    // 16 n's
            u16 q0[16], q1[16];
            if (bf) {
                const u16* w0 = (const u16*)W + (size_t)(kg + 2 * p) * 768 + n0 + nseg;
                ((uint4*)q0)[0] = ((const uint4*)w0)[0];
                ((uint4*)q0)[1] = ((const uint4*)w0)[1];
                ((uint4*)q1)[0] = ((const uint4*)(w0 + 768))[0];
                ((uint4*)q1)[1] = ((const uint4*)(w0 + 768))[1];
            } else {
                const float* w0 = (const float*)W + (size_t)(kg + 2 * p) * 768 + n0 + nseg;
#pragma unroll
                for (int e = 0; e < 4; ++e) {
                    float4 v0 = ((const float4*)w0)[e];
                    float4 v1 = ((const float4*)(w0 + 768))[e];
                    q0[4 * e] = f2bf(v0.x); q0[4 * e + 1] = f2bf(v0.y);
                    q0[4 * e + 2] = f2bf(v0.z); q0[4 * e + 3] = f2bf(v0.w);
                    q1[4 * e] = f2bf(v1.x); q1[4 * e + 1] = f2bf(v1.y);
                    q1[4 * e + 2] = f2bf(v1.z); q1[4 * e + 3] = f2bf(v1.w);
                }
            }
#pragma unroll
            for (int e = 0; e < 16; ++e)
                *(ushort2*)(Bs + (nseg + e) * 136 + 2 * p) = make_ushort2(q0[e], q1[e]);
        } else {
            // conv: within a 128-chunk, kb = kg/768 is constant (768 = 6*128)
            const int kb = kg / 768;
            const int i0c = kg - kb * 768;
            u16 tmp[32];
            if (bf) {
                const u16* wp = (const u16*)W + (size_t)(n0 + r) * 2304 + (size_t)(i0c + cseg) * 3 + kb;
#pragma unroll
                for (int j = 0; j < 32; ++j) tmp[j] = wp[j * 3];
            } else {
                const float* wp = (const float*)W + (size_t)(n0 + r) * 2304 + (size_t)(i0c + cseg) * 3 + kb;
#pragma unroll
                for (int j = 0; j < 32; ++j) tmp[j] = f2bf(wp[j * 3]);
            }
            u16* dst = Bs + r * 136 + cseg;
#pragma unroll
            for (int qq = 0; qq < 8; ++qq)
                ((ushort4*)dst)[qq] = ((ushort4*)tmp)[qq];
        }
        __syncthreads();
        const u16* ap = As + (wave * 16 + lm) * 136 + lq * 8;
        const u16* bp = Bs + lm * 136 + lq * 8;
#pragma unroll
        for (int ks = 0; ks < 4; ++ks) {
            short8 af = *(const short8*)(ap + ks * 32);
#pragma unroll
            for (int nf = 0; nf < 4; ++nf) {
                short8 bfr = *(const short8*)(bp + nf * 16 * 136 + ks * 32);
                acc[nf] = __builtin_amdgcn_mfma_f32_16x16x32_bf16(af, bfr, acc[nf], 0, 0, 0);
            }
        }
        __syncthreads();
    }
#pragma unroll
    for (int nf = 0; nf < 4; ++nf) {
#pragma unroll
        for (int rg = 0; rg < 4; ++rg) {
            const int row = wave * 16 + lq * 4 + rg;
            const int col = n0 + nf * 16 + lm;
            atomicAdd(out + (size_t)row * ostride + col, acc[nf][rg]);
        }
    }
}

__device__ __forceinline__ float block_sum(float v, float* red) {
#pragma unroll
    for (int m = 1; m < 64; m <<= 1) v += __shfl_xor(v, m, 64);
    const int wave = threadIdx.x >> 6, lane = threadIdx.x & 63;
    if (lane == 0) red[wave] = v;
    __syncthreads();
    const float r = red[0] + red[1] + red[2] + red[3];
    __syncthreads();
    return r;
}

// ---------------------------------------------------------------------------
// Monolithic kernel, grid = 768 x 256.
// stage0: pooling (768 units, atomicAdd into zeroed sentF) | gbar |
// stage1: GEMM-A (216 units) | gbar | stage2: GEMM-B (216 units) | gbar |
// stage3: refine chains + softmax + fc2 (64 units)
// ---------------------------------------------------------------------------
__global__ __launch_bounds__(256) void kmono(
    const void* __restrict__ bert, const int* __restrict__ sb,
    const void* __restrict__ target,
    const void* __restrict__ gc1w, const void* __restrict__ gc1b,
    const void* __restrict__ gc2w, const void* __restrict__ gc2b,
    const void* __restrict__ c1w, const void* __restrict__ c1b,
    const void* __restrict__ c2w, const void* __restrict__ c2b,
    const void* __restrict__ lng, const void* __restrict__ lnb,
    const void* __restrict__ fc2w, const void* __restrict__ fc2b,
    void* __restrict__ outp, float* __restrict__ ws)
{
    __shared__ u16 As[64 * 136];
    __shared__ u16 Bs[64 * 136];
    __shared__ float red[4];
    const int t = threadIdx.x;
    const int blk = blockIdx.x;

    const bool bf = detect_bf16((const u16*)bert);
    const bool is64 = (sb[1] == 0);

    float* sentF = ws;                      // 147456 floats (zeroed by memset)
    float* accs  = ws + 147456;             // 245760 floats (zeroed by memset)
    float* g1acc = accs;                    // 64 x 768
    float* c1acc = g1acc + 49152;           // 64 x 1536 [c1_6 | c1_7]
    float* g2acc = c1acc + 98304;           // 64 x 768
    float* c2acc = g2acc + 49152;           // 64 x 768
    unsigned* cnts = (unsigned*)(accs + 245760);  // 3 barrier counters (zeroed)

    // ---- stage 0: segment mean pooling, atomicAdd into sentF ----
    {
        const int u = blk;
        const int q = u & 3, v = u >> 2;       // v in [0,192)
        const int b = v / 3, si = v - 3 * (v / 3), s = 5 + si;
        const int i0 = b * 9 + s, i1 = i0 + 1;
        int st = is64 ? sb[2 * i0] : sb[i0];
        int en = is64 ? sb[2 * i1] : sb[i1];
        st = st < 0 ? 0 : (st > 511 ? 511 : st);
        en = en <= st ? st + 1 : (en > 512 ? 512 : en);
        const int n = en - st;
        const int r0 = st + (n * q) / 4;
        const int r1 = st + (n * (q + 1)) / 4;
        float a0 = 0.f, a1 = 0.f, a2 = 0.f;
        if (bf) {
            const u16* base = (const u16*)bert + (size_t)b * 512 * 768;
            int l = r0;
            for (; l + 1 < r1; l += 2) {
                const u16* p0 = base + (size_t)l * 768;
                const u16* p1 = p0 + 768;
                a0 += bf2f(p0[t]) + bf2f(p1[t]);
                a1 += bf2f(p0[t + 256]) + bf2f(p1[t + 256]);
                a2 += bf2f(p0[t + 512]) + bf2f(p1[t + 512]);
            }
            if (l < r1) {
                const u16* p0 = base + (size_t)l * 768;
                a0 += bf2f(p0[t]);
                a1 += bf2f(p0[t + 256]);
                a2 += bf2f(p0[t + 512]);
            }
        } else {
            const float* base = (const float*)bert + (size_t)b * 512 * 768;
            int l = r0;
            for (; l + 1 < r1; l += 2) {
                const float* p0 = base + (size_t)l * 768;
                const float* p1 = p0 + 768;
                a0 += p0[t] + p1[t];
                a1 += p0[t + 256] + p1[t + 256];
                a2 += p0[t + 512] + p1[t + 512];
            }
            if (l < r1) {
                const float* p0 = base + (size_t)l * 768;
                a0 += p0[t];
                a1 += p0[t + 256];
                a2 += p0[t + 512];
            }
        }
        const float inv = 1.0f / (float)n;
        float* o = sentF + b * 2304 + si * 768;
        atomicAdd(o + t, a0 * inv);
        atomicAdd(o + t + 256, a1 * inv);
        atomicAdd(o + t + 512, a2 * inv);
    }

    gbar(cnts + 0, NBLK);

    // ---- stage 1: GEMM-A (216 units, K-chunks of 256) ----
    if (blk < 216) {
        const int u = blk;
        if (u < 36) {
            gemm_core<0, 0>(sentF + 1536, 2304, nullptr, gc1w, bf, g1acc, 768,
                            (u / 3) * 64, (u % 3) * 256, 2, As, Bs);
        } else if (u < 144) {
            const int v = u - 36;
            gemm_core<0, 1>(sentF, 2304, nullptr, c1w, bf, c1acc, 1536,
                            (v / 9) * 64, (v % 9) * 256, 2, As, Bs);
        } else {
            const int v = u - 144;
            gemm_core<0, 1>(sentF + 768, 2304, nullptr, c1w, bf, c1acc + 768, 1536,
                            (v / 6) * 64, (v % 6) * 256, 2, As, Bs);
        }
    }

    gbar(cnts + 1, NBLK);

    // ---- stage 2: GEMM-B (216 units, K-chunks of 128) ----
    if (blk < 216) {
        const int u = blk;
        if (u < 72) {
            gemm_core<1, 0>(g1acc, 768, gc1b, gc2w, bf, g2acc, 768,
                            (u / 6) * 64, (u % 6) * 128, 1, As, Bs);
        } else {
            const int v = u - 72;
            gemm_core<1, 1>(c1acc, 1536, c1b, c2w, bf, c2acc, 768,
                            (v / 12) * 64, (v % 12) * 128, 1, As, Bs);
        }
    }

    gbar(cnts + 2, NBLK);

    // ---- stage 3: per-batch refine chains + softmax + fc2 (64 units) ----
    if (blk < 64) {
        const int b = blk;
        float s_[3], g_[3], bb_[3];
        const float* srow = sentF + b * 2304 + 1536;  // sent7
#pragma unroll
        for (int i = 0; i < 3; ++i) {
            const int d = t + 256 * i;
            s_[i] = srow[d];
            g_[i] = ldv(lng, d, bf);
            bb_[i] = ldv(lnb, d, bf);
        }

        auto refine2 = [&](float* yv) {
#pragma unroll
            for (int it = 0; it < 2; ++it) {
                const float c = block_sum(yv[0] * s_[0] + yv[1] * s_[1] + yv[2] * s_[2], red);
                float tt[3], sm = 0.0f, sq = 0.0f;
#pragma unroll
                for (int i = 0; i < 3; ++i) {
                    tt[i] = sigm(c * s_[i]);
                    sm += tt[i];
                    sq += tt[i] * tt[i];
                }
                const float m = block_sum(sm, red) * (1.0f / 768.0f);
                const float q = block_sum(sq, red) * (1.0f / 768.0f);
                const float inv = rsqrtf(fmaxf(q - m * m, 0.0f) + 1e-5f);
#pragma unroll
                for (int i = 0; i < 3; ++i)
                    yv[i] = 0.5f * ((tt[i] - m) * inv * g_[i] + bb_[i]) + s_[i];
            }
        };

        float a3[3], a4[3], a5[3], y[3];
#pragma unroll
        for (int i = 0; i < 3; ++i) {
            const int d = t + 256 * i;
            y[i] = tanhf(g2acc[b * 768 + d] + ldv(gc2b, d, bf));
        }
        refine2(y);
        a3[0] = y[0]; a3[1] = y[1]; a3[2] = y[2];
#pragma unroll
        for (int i = 0; i < 3; ++i) {
            const int d = t + 256 * i;
            y[i] = tanhf(c2acc[b * 768 + d] + ldv(c2b, d, bf));
        }
        refine2(y);
        a4[0] = y[0]; a4[1] = y[1]; a4[2] = y[2];
        const float ss = block_sum(s_[0] * s_[0] + s_[1] * s_[1] + s_[2] * s_[2], red);
#pragma unroll
        for (int i = 0; i < 3; ++i) y[i] = sigm(ss * s_[i]);
        refine2(y);
        a5[0] = y[0]; a5[1] = y[1]; a5[2] = y[2];

        float tg[3];
#pragma unroll
        for (int i = 0; i < 3; ++i) tg[i] = ldv(target, t + 256 * i, bf);  // target[0]
        const float u0 = block_sum(a3[0] * tg[0] + a3[1] * tg[1] + a3[2] * tg[2], red);
        const float u1 = block_sum(a4[0] * tg[0] + a4[1] * tg[1] + a4[2] * tg[2], red);
        const float u2 = block_sum(a5[0] * tg[0] + a5[1] * tg[1] + a5[2] * tg[2], red);
        const float mx = fmaxf(u0, fmaxf(u1, u2));
        const float e0 = __expf(u0 - mx), e1 = __expf(u1 - mx), e2 = __expf(u2 - mx);
        const float es = e0 + e1 + e2;
        const float w0 = e0 / es, w1 = e1 / es, w2 = e2 / es;

        float p0 = 0.0f, p1 = 0.0f, p2 = 0.0f;
#pragma unroll
        for (int i = 0; i < 3; ++i) {
            const int d = t + 256 * i;
            const float va = w0 * a3[i], vb = w1 * a4[i], vc = w2 * a5[i];
            p0 += va * ldv(fc2w, d * 3 + 0, bf) + vb * ldv(fc2w, (768 + d) * 3 + 0, bf) + vc * ldv(fc2w, (1536 + d) * 3 + 0, bf);
            p1 += va * ldv(fc2w, d * 3 + 1, bf) + vb * ldv(fc2w, (768 + d) * 3 + 1, bf) + vc * ldv(fc2w, (1536 + d) * 3 + 1, bf);
            p2 += va * ldv(fc2w, d * 3 + 2, bf) + vb * ldv(fc2w, (768 + d) * 3 + 2, bf) + vc * ldv(fc2w, (1536 + d) * 3 + 2, bf);
        }
        p0 = block_sum(p0, red);
        p1 = block_sum(p1, red);
        p2 = block_sum(p2, red);
        if (t == 0) {
            const float o0 = p0 + ldv(fc2b, 0, bf);
            const float o1 = p1 + ldv(fc2b, 1, bf);
            const float o2 = p2 + ldv(fc2b, 2, bf);
            if (bf) {
                ((u16*)outp)[b * 3 + 0] = f2bf(o0);
                ((u16*)outp)[b * 3 + 1] = f2bf(o1);
                ((u16*)outp)[b * 3 + 2] = f2bf(o2);
            } else {
                ((float*)outp)[b * 3 + 0] = o0;
                ((float*)outp)[b * 3 + 1] = o1;
                ((float*)outp)[b * 3 + 2] = o2;
            }
        }
    }
}

extern "C" void kernel_launch(void* const* d_in, const int* in_sizes, int n_in,
                              void* d_out, int out_size, void* d_ws, size_t ws_size,
                              hipStream_t stream) {
    const void* bert   = d_in[0];
    const void* target = d_in[1];
    const void* gc1w   = d_in[2];
    const void* gc1b   = d_in[3];
    const void* gc2w   = d_in[4];
    const void* gc2b   = d_in[5];
    const void* c1w    = d_in[6];
    const void* c1b    = d_in[7];
    const void* c2w    = d_in[8];
    const void* c2b    = d_in[9];
    const void* lng    = d_in[10];
    const void* lnb    = d_in[11];
    const void* fc2w   = d_in[12];
    const void* fc2b   = d_in[13];
    const int*  sb     = (const int*)d_in[14];

    // ws layout: sentF (147456 f) | accs (245760 f) | 3 barrier counters
    // One memset zeroes everything: 393216 floats + 12 bytes.
    hipMemsetAsync(d_ws, 0, 393216 * 4 + 12, stream);

    kmono<<<NBLK, 256, 0, stream>>>(
        bert, sb, target, gc1w, gc1b, gc2w, gc2b, c1w, c1b, c2w, c2b,
        lng, lnb, fc2w, fc2b, d_out, (float*)d_ws);
}

// Round 3
// 295.566 us; speedup vs baseline: 1.5668x; 1.0015x over previous
//
#include <hip/hip_runtime.h>

// Problem: B=64, L=512, D=768, S=8, HOP=3, LAMB=0.5
// Output depends only on sentence segments s in {5,6,7}.
// R7: monolithic kernel, grid=192x256, fence-free barriers (proven R6), but
// ZERO RMW atomics (R6 had 2.36M device-scope atomicAdds serializing at the
// coherence point -> ~130us) and <=108 pollers with long s_sleep (R6 had 552
// pollers at 290ns period saturating IF$).
//   - pooling: 1 block per (b,seg), unique plain outputs
//   - GEMMs: K-split into 3 partial slabs, ONE writer per address; consumer
//     stage sums the 3 partials during staging (XMODE 3)
//   - all cross-stage stores are relaxed AGENT-scope atomic stores
//     (write-through to IF$, no L2 dirty lines, no fences needed)
//   - blocks with no further work pre-bump their remaining barrier counters
//     and exit (cnt targets = 192 always)
// ws: [16 u32 counters(64B, memset)] sentF 64x2304 | g1p 3x(64x768) |
//     c1p 3x(64x1536) | g2p 3x(64x768) | c2p 3x(64x768)  => ~3.54 MB.

typedef unsigned short u16;
typedef short short8 __attribute__((ext_vector_type(8)));
typedef float f32x4 __attribute__((ext_vector_type(4)));

#define NBLK 192

__device__ __forceinline__ float bf2f(u16 h) {
    unsigned int u = ((unsigned int)h) << 16;
    float f;
    __builtin_memcpy(&f, &u, 4);
    return f;
}
__device__ __forceinline__ u16 f2bf(float f) {
    unsigned int u;
    __builtin_memcpy(&u, &f, 4);
    u = (u + 0x7fffu + ((u >> 16) & 1u)) >> 16;  // RNE
    return (u16)u;
}
__device__ __forceinline__ float sigm(float x) { return 1.0f / (1.0f + __expf(-x)); }

__device__ __forceinline__ float ldv(const void* p, long i, bool bf) {
    return bf ? bf2f(((const u16*)p)[i]) : ((const float*)p)[i];
}

// write-through store, visible device-wide once vmcnt==0 (no L2 dirty line)
__device__ __forceinline__ void gstore(float* p, float v) {
    __hip_atomic_store(p, v, __ATOMIC_RELAXED, __HIP_MEMORY_SCOPE_AGENT);
}
__device__ __forceinline__ void bump(unsigned* c) {
    __hip_atomic_fetch_add(c, 1u, __ATOMIC_RELAXED, __HIP_MEMORY_SCOPE_AGENT);
}

// dtype detector: even-indexed u16s of fp32 N(0,1) data are mantissa bits
// (uniform -> ~6% in exponent window); of bf16 data they are values (~99%).
__device__ __forceinline__ bool detect_bf16(const u16* bert) {
    int hits = 0;
#pragma unroll
    for (int i = 0; i < 256; i += 2) {
        const int e = (bert[i] >> 7) & 0xFF;
        hits += (e >= 115 && e <= 130) ? 1 : 0;
    }
    return hits > 64;
}

// Fence-free arrive+wait barrier (leader thread). All data writes are
// write-through agent stores, acked at the coherence point when vmcnt==0.
__device__ __forceinline__ void gbar(unsigned* cnt, unsigned target) {
    __syncthreads();
    if (threadIdx.x == 0) {
        asm volatile("s_waitcnt vmcnt(0)" ::: "memory");
        bump(cnt);
        int polls = 0;
        while (__hip_atomic_load(cnt, __ATOMIC_RELAXED, __HIP_MEMORY_SCOPE_AGENT) < target) {
            __builtin_amdgcn_s_sleep(32);   // ~2k cycles: low IF$ poll traffic
            if (++polls > (1 << 20)) break; // deadlock bail: wrong > hang
        }
    }
    __syncthreads();
}

// ---------------------------------------------------------------------------
// GEMM core: out(64 x Nout) = x(64 x K-chunk) @ B^T, 64x64 tile, K-chunk
// [k0, k0+kiters*128). Output written ONCE per address (no accumulation).
// XMODE 0: x raw fp32. XMODE 3: x = tanh(x0+x1+x2 + bias[k%768]) where
//   x1 = x + pslab, x2 = x + 2*pslab (partial slabs).
// WMODE 0: W is [k][n] row-major, n-dim 768. WMODE 1: conv weights (O,I,3),
//   tap kb = kg/768 (recomputed per 128-iter; chunks may cross 768).
// mfma_f32_16x16x32_bf16; C/D col=lane&15, row=quad*4+reg.
// ---------------------------------------------------------------------------
template <int XMODE, int WMODE>
__device__ __forceinline__ void gemm_core(
    const float* __restrict__ x, int xstride, int pslab,
    const void* __restrict__ bias, const void* __restrict__ W, bool bf,
    float* __restrict__ out, int ostride,
    int n0, int k0, int kiters, u16* As, u16* Bs)
{
    const int t = threadIdx.x;
    const int r = t >> 2;             // 0..63
    const int cseg = (t & 3) * 32;    // 0,32,64,96
    const int wave = t >> 6, lane = t & 63;
    const int lm = lane & 15, lq = lane >> 4;
    f32x4 acc[4] = {};

    for (int kk = 0; kk < kiters * 128; kk += 128) {
        const int kg = k0 + kk;
        // ---- stage x -> As (fp32 -> bf16), row stride 136 ----
        {
            const float* xp = x + (size_t)r * xstride + (kg + cseg);
            u16* dst = As + r * 136 + cseg;
#pragma unroll
            for (int i = 0; i < 8; ++i) {
                float4 v = ((const float4*)xp)[i];
                if (XMODE == 3) {
                    float4 v1 = ((const float4*)(xp + pslab))[i];
                    float4 v2 = ((const float4*)(xp + 2 * pslab))[i];
                    v.x += v1.x + v2.x;
                    v.y += v1.y + v2.y;
                    v.z += v1.z + v2.z;
                    v.w += v1.w + v2.w;
                    int kb = kg + cseg + i * 4;
                    if (kb >= 768) kb -= 768;   // K <= 1536, 4-aligned
                    v.x = tanhf(v.x + ldv(bias, kb, bf));
                    v.y = tanhf(v.y + ldv(bias, kb + 1, bf));
                    v.z = tanhf(v.z + ldv(bias, kb + 2, bf));
                    v.w = tanhf(v.w + ldv(bias, kb + 3, bf));
                }
                ((ushort4*)dst)[i] = make_ushort4(f2bf(v.x), f2bf(v.y), f2bf(v.z), f2bf(v.w));
            }
        }
        // ---- stage W -> Bs as [n][k], row stride 136 ----
        if (WMODE == 0) {
            const int p = t >> 2;             // k-pair: k = 2p, 2p+1
            const int nseg = (t & 3) * 16;    // 16 n's
            u16 q0[16], q1[16];
            if (bf) {
                const u16* w0 = (const u16*)W + (size_t)(kg + 2 * p) * 768 + n0 + nseg;
                ((uint4*)q0)[0] = ((const uint4*)w0)[0];
                ((uint4*)q0)[1] = ((const uint4*)w0)[1];
                ((uint4*)q1)[0] = ((const uint4*)(w0 + 768))[0];
                ((uint4*)q1)[1] = ((const uint4*)(w0 + 768))[1];
            } else {
                const float* w0 = (const float*)W + (size_t)(kg + 2 * p) * 768 + n0 + nseg;
#pragma unroll
                for (int e = 0; e < 4; ++e) {
                    float4 v0 = ((const float4*)w0)[e];
                    float4 v1 = ((const float4*)(w0 + 768))[e];
                    q0[4 * e] = f2bf(v0.x); q0[4 * e + 1] = f2bf(v0.y);
                    q0[4 * e + 2] = f2bf(v0.z); q0[4 * e + 3] = f2bf(v0.w);
                    q1[4 * e] = f2bf(v1.x); q1[4 * e + 1] = f2bf(v1.y);
                    q1[4 * e + 2] = f2bf(v1.z); q1[4 * e + 3] = f2bf(v1.w);
                }
            }
#pragma unroll
            for (int e = 0; e < 16; ++e)
                *(ushort2*)(Bs + (nseg + e) * 136 + 2 * p) = make_ushort2(q0[e], q1[e]);
        } else {
            const int kb = kg / 768;          // conv tap (const per 128-iter)
            const int i0c = kg - kb * 768;
            u16 tmp[32];
            if (bf) {
                const u16* wp = (const u16*)W + (size_t)(n0 + r) * 2304 + (size_t)(i0c + cseg) * 3 + kb;
#pragma unroll
                for (int j = 0; j < 32; ++j) tmp[j] = wp[j * 3];
            } else {
                const float* wp = (const float*)W + (size_t)(n0 + r) * 2304 + (size_t)(i0c + cseg) * 3 + kb;
#pragma unroll
                for (int j = 0; j < 32; ++j) tmp[j] = f2bf(wp[j * 3]);
            }
            u16* dst = Bs + r * 136 + cseg;
#pragma unroll
            for (int qq = 0; qq < 8; ++qq)
                ((ushort4*)dst)[qq] = ((ushort4*)tmp)[qq];
        }
        __syncthreads();
        const u16* ap = As + (wave * 16 + lm) * 136 + lq * 8;
        const u16* bp = Bs + lm * 136 + lq * 8;
#pragma unroll
        for (int ks = 0; ks < 4; ++ks) {
            short8 af = *(const short8*)(ap + ks * 32);
#pragma unroll
            for (int nf = 0; nf < 4; ++nf) {
                short8 bfr = *(const short8*)(bp + nf * 16 * 136 + ks * 32);
                acc[nf] = __builtin_amdgcn_mfma_f32_16x16x32_bf16(af, bfr, acc[nf], 0, 0, 0);
            }
        }
        __syncthreads();
    }
    // unique-writer output: write-through agent stores (no RMW)
#pragma unroll
    for (int nf = 0; nf < 4; ++nf) {
#pragma unroll
        for (int rg = 0; rg < 4; ++rg) {
            const int row = wave * 16 + lq * 4 + rg;
            const int col = n0 + nf * 16 + lm;
            gstore(out + (size_t)row * ostride + col, acc[nf][rg]);
        }
    }
}

__device__ __forceinline__ float block_sum(float v, float* red) {
#pragma unroll
    for (int m = 1; m < 64; m <<= 1) v += __shfl_xor(v, m, 64);
    const int wave = threadIdx.x >> 6, lane = threadIdx.x & 63;
    if (lane == 0) red[wave] = v;
    __syncthreads();
    const float r = red[0] + red[1] + red[2] + red[3];
    __syncthreads();
    return r;
}

// ---------------------------------------------------------------------------
// Monolithic kernel, grid = 192 x 256.
// stage0: pooling (192 units) | bar0 | stage1: GEMM-A (108 units) | bar1 |
// stage2: GEMM-B (72 units) | bar2 | stage3: refine+softmax+fc2 (64 units)
// Early exit: blk>=108 after stage0; blk in [72,108) after stage1;
// blk in [64,72) after stage2. Counter targets always 192.
// ---------------------------------------------------------------------------
__global__ __launch_bounds__(256) void kmono(
    const void* __restrict__ bert, const int* __restrict__ sb,
    const void* __restrict__ target,
    const void* __restrict__ gc1w, const void* __restrict__ gc1b,
    const void* __restrict__ gc2w, const void* __restrict__ gc2b,
    const void* __restrict__ c1w, const void* __restrict__ c1b,
    const void* __restrict__ c2w, const void* __restrict__ c2b,
    const void* __restrict__ lng, const void* __restrict__ lnb,
    const void* __restrict__ fc2w, const void* __restrict__ fc2b,
    void* __restrict__ outp, float* __restrict__ ws)
{
    __shared__ u16 As[64 * 136];
    __shared__ u16 Bs[64 * 136];
    __shared__ float red[4];
    const int t = threadIdx.x;
    const int blk = blockIdx.x;

    const bool bf = detect_bf16((const u16*)bert);
    const bool is64 = (sb[1] == 0);

    unsigned* cnts = (unsigned*)ws;         // 16 u32 (64 B, memset to 0)
    float* sentF = ws + 16;                 // 64 x 2304
    float* g1p   = sentF + 147456;          // 3 x (64 x 768)
    float* c1p   = g1p + 147456;            // 3 x (64 x 1536)
    float* g2p   = c1p + 294912;            // 3 x (64 x 768)
    float* c2p   = g2p + 147456;            // 3 x (64 x 768)

    // ---- stage 0: segment mean pooling, one block per (b,si) ----
    {
        const int b = blk / 3, si = blk - 3 * (blk / 3), s = 5 + si;
        const int i0 = b * 9 + s, i1 = i0 + 1;
        int st = is64 ? sb[2 * i0] : sb[i0];
        int en = is64 ? sb[2 * i1] : sb[i1];
        st = st < 0 ? 0 : (st > 511 ? 511 : st);
        en = en <= st ? st + 1 : (en > 512 ? 512 : en);
        const int n = en - st;
        float a0 = 0.f, a1 = 0.f, a2 = 0.f;
        if (bf) {
            const u16* base = (const u16*)bert + (size_t)b * 512 * 768;
            int l = st;
            for (; l + 1 < en; l += 2) {
                const u16* p0 = base + (size_t)l * 768;
                const u16* p1 = p0 + 768;
                a0 += bf2f(p0[t]) + bf2f(p1[t]);
                a1 += bf2f(p0[t + 256]) + bf2f(p1[t + 256]);
                a2 += bf2f(p0[t + 512]) + bf2f(p1[t + 512]);
            }
            if (l < en) {
                const u16* p0 = base + (size_t)l * 768;
                a0 += bf2f(p0[t]);
                a1 += bf2f(p0[t + 256]);
                a2 += bf2f(p0[t + 512]);
            }
        } else {
            const float* base = (const float*)bert + (size_t)b * 512 * 768;
            int l = st;
            for (; l + 1 < en; l += 2) {
                const float* p0 = base + (size_t)l * 768;
                const float* p1 = p0 + 768;
                a0 += p0[t] + p1[t];
                a1 += p0[t + 256] + p1[t + 256];
                a2 += p0[t + 512] + p1[t + 512];
            }
            if (l < en) {
                const float* p0 = base + (size_t)l * 768;
                a0 += p0[t];
                a1 += p0[t + 256];
                a2 += p0[t + 512];
            }
        }
        const float inv = 1.0f / (float)n;
        float* o = sentF + b * 2304 + si * 768;
        gstore(o + t, a0 * inv);
        gstore(o + t + 256, a1 * inv);
        gstore(o + t + 512, a2 * inv);
    }

    if (blk >= 108) {  // no more work: pre-bump all counters, exit
        __syncthreads();
        if (t == 0) {
            asm volatile("s_waitcnt vmcnt(0)" ::: "memory");
            bump(cnts + 0); bump(cnts + 1); bump(cnts + 2);
        }
        return;
    }
    gbar(cnts + 0, NBLK);

    // ---- stage 1: GEMM-A (108 units): g1 (12x3), c1_6 (12x3), c1_7 (12x3)
    {
        const int u = blk;
        if (u < 36) {
            const int nt = u / 3, jc = u % 3;
            gemm_core<0, 0>(sentF + 1536, 2304, 0, nullptr, gc1w, bf,
                            g1p + jc * 49152, 768, nt * 64, jc * 256, 2, As, Bs);
        } else if (u < 72) {
            const int v = u - 36, nt = v / 3, jc = v % 3;
            gemm_core<0, 1>(sentF, 2304, 0, nullptr, c1w, bf,
                            c1p + jc * 98304, 1536, nt * 64, jc * 768, 6, As, Bs);
        } else {
            const int v = u - 72, nt = v / 3, jc = v % 3;
            gemm_core<0, 1>(sentF + 768, 2304, 0, nullptr, c1w, bf,
                            c1p + jc * 98304 + 768, 1536, nt * 64, jc * 512, 4, As, Bs);
        }
    }

    if (blk >= 72) {
        __syncthreads();
        if (t == 0) {
            asm volatile("s_waitcnt vmcnt(0)" ::: "memory");
            bump(cnts + 1); bump(cnts + 2);
        }
        return;
    }
    gbar(cnts + 1, NBLK);

    // ---- stage 2: GEMM-B (72 units): g2 (12x3), c2 (12x3) ----
    {
        const int u = blk;
        if (u < 36) {
            const int nt = u / 3, jc = u % 3;
            gemm_core<3, 0>(g1p, 768, 49152, gc1b, gc2w, bf,
                            g2p + jc * 49152, 768, nt * 64, jc * 256, 2, As, Bs);
        } else {
            const int v = u - 36, nt = v / 3, jc = v % 3;
            gemm_core<3, 1>(c1p, 1536, 98304, c1b, c2w, bf,
                            c2p + jc * 49152, 768, nt * 64, jc * 512, 4, As, Bs);
        }
    }

    if (blk >= 64) {
        __syncthreads();
        if (t == 0) {
            asm volatile("s_waitcnt vmcnt(0)" ::: "memory");
            bump(cnts + 2);
        }
        return;
    }
    gbar(cnts + 2, NBLK);

    // ---- stage 3: per-batch refine chains + softmax + fc2 (64 units) ----
    {
        const int b = blk;
        float s_[3], g_[3], bb_[3];
        const float* srow = sentF + b * 2304 + 1536;  // sent7
#pragma unroll
        for (int i = 0; i < 3; ++i) {
            const int d = t + 256 * i;
            s_[i] = srow[d];
            g_[i] = ldv(lng, d, bf);
            bb_[i] = ldv(lnb, d, bf);
        }

        auto refine2 = [&](float* yv) {
#pragma unroll
            for (int it = 0; it < 2; ++it) {
                const float c = block_sum(yv[0] * s_[0] + yv[1] * s_[1] + yv[2] * s_[2], red);
                float tt[3], sm = 0.0f, sq = 0.0f;
#pragma unroll
                for (int i = 0; i < 3; ++i) {
                    tt[i] = sigm(c * s_[i]);
                    sm += tt[i];
                    sq += tt[i] * tt[i];
                }
                const float m = block_sum(sm, red) * (1.0f / 768.0f);
                const float q = block_sum(sq, red) * (1.0f / 768.0f);
                const float inv = rsqrtf(fmaxf(q - m * m, 0.0f) + 1e-5f);
#pragma unroll
                for (int i = 0; i < 3; ++i)
                    yv[i] = 0.5f * ((tt[i] - m) * inv * g_[i] + bb_[i]) + s_[i];
            }
        };

        float a3[3], a4[3], a5[3], y[3];
#pragma unroll
        for (int i = 0; i < 3; ++i) {
            const int d = t + 256 * i;
            const float gs = g2p[b * 768 + d] + g2p[49152 + b * 768 + d] + g2p[98304 + b * 768 + d];
            y[i] = tanhf(gs + ldv(gc2b, d, bf));
        }
        refine2(y);
        a3[0] = y[0]; a3[1] = y[1]; a3[2] = y[2];
#pragma unroll
        for (int i = 0; i < 3; ++i) {
            const int d = t + 256 * i;
            const float cs = c2p[b * 768 + d] + c2p[49152 + b * 768 + d] + c2p[98304 + b * 768 + d];
            y[i] = tanhf(cs + ldv(c2b, d, bf));
        }
        refine2(y);
        a4[0] = y[0]; a4[1] = y[1]; a4[2] = y[2];
        const float ss = block_sum(s_[0] * s_[0] + s_[1] * s_[1] + s_[2] * s_[2], red);
#pragma unroll
        for (int i = 0; i < 3; ++i) y[i] = sigm(ss * s_[i]);
        refine2(y);
        a5[0] = y[0]; a5[1] = y[1]; a5[2] = y[2];

        float tg[3];
#pragma unroll
        for (int i = 0; i < 3; ++i) tg[i] = ldv(target, t + 256 * i, bf);  // target[0]
        const float u0 = block_sum(a3[0] * tg[0] + a3[1] * tg[1] + a3[2] * tg[2], red);
        const float u1 = block_sum(a4[0] * tg[0] + a4[1] * tg[1] + a4[2] * tg[2], red);
        const float u2 = block_sum(a5[0] * tg[0] + a5[1] * tg[1] + a5[2] * tg[2], red);
        const float mx = fmaxf(u0, fmaxf(u1, u2));
        const float e0 = __expf(u0 - mx), e1 = __expf(u1 - mx), e2 = __expf(u2 - mx);
        const float es = e0 + e1 + e2;
        const float w0 = e0 / es, w1 = e1 / es, w2 = e2 / es;

        float p0 = 0.0f, p1 = 0.0f, p2 = 0.0f;
#pragma unroll
        for (int i = 0; i < 3; ++i) {
            const int d = t + 256 * i;
            const float va = w0 * a3[i], vb = w1 * a4[i], vc = w2 * a5[i];
            p0 += va * ldv(fc2w, d * 3 + 0, bf) + vb * ldv(fc2w, (768 + d) * 3 + 0, bf) + vc * ldv(fc2w, (1536 + d) * 3 + 0, bf);
            p1 += va * ldv(fc2w, d * 3 + 1, bf) + vb * ldv(fc2w, (768 + d) * 3 + 1, bf) + vc * ldv(fc2w, (1536 + d) * 3 + 1, bf);
            p2 += va * ldv(fc2w, d * 3 + 2, bf) + vb * ldv(fc2w, (768 + d) * 3 + 2, bf) + vc * ldv(fc2w, (1536 + d) * 3 + 2, bf);
        }
        p0 = block_sum(p0, red);
        p1 = block_sum(p1, red);
        p2 = block_sum(p2, red);
        if (t == 0) {
            const float o0 = p0 + ldv(fc2b, 0, bf);
            const float o1 = p1 + ldv(fc2b, 1, bf);
            const float o2 = p2 + ldv(fc2b, 2, bf);
            if (bf) {
                ((u16*)outp)[b * 3 + 0] = f2bf(o0);
                ((u16*)outp)[b * 3 + 1] = f2bf(o1);
                ((u16*)outp)[b * 3 + 2] = f2bf(o2);
            } else {
                ((float*)outp)[b * 3 + 0] = o0;
                ((float*)outp)[b * 3 + 1] = o1;
                ((float*)outp)[b * 3 + 2] = o2;
            }
        }
    }
}

extern "C" void kernel_launch(void* const* d_in, const int* in_sizes, int n_in,
                              void* d_out, int out_size, void* d_ws, size_t ws_size,
                              hipStream_t stream) {
    const void* bert   = d_in[0];
    const void* target = d_in[1];
    const void* gc1w   = d_in[2];
    const void* gc1b   = d_in[3];
    const void* gc2w   = d_in[4];
    const void* gc2b   = d_in[5];
    const void* c1w    = d_in[6];
    const void* c1b    = d_in[7];
    const void* c2w    = d_in[8];
    const void* c2b    = d_in[9];
    const void* lng    = d_in[10];
    const void* lnb    = d_in[11];
    const void* fc2w   = d_in[12];
    const void* fc2b   = d_in[13];
    const int*  sb     = (const int*)d_in[14];

    // only the 3 barrier counters need zeroing (no accumulation anywhere)
    hipMemsetAsync(d_ws, 0, 64, stream);

    kmono<<<NBLK, 256, 0, stream>>>(
        bert, sb, target, gc1w, gc1b, gc2w, gc2b, c1w, c1b, c2w, c2b,
        lng, lnb, fc2w, fc2b, d_out, (float*)d_ws);
}

// Round 4
// 266.493 us; speedup vs baseline: 1.7378x; 1.1091x over previous
//
#include <hip/hip_runtime.h>

// Problem: B=64, L=512, D=768, S=8, HOP=3, LAMB=0.5
// Output depends only on sentence segments s in {5,6,7}.
// R8: back to SPLIT kernels (empirically: split R4=224us total beat every
// fused variant ~295us; the fused low-occupancy barrier tail stalls in ways
// no counter explains). 4 dispatches, ZERO atomics, ZERO memset:
//   kA pool (768 blk): 4-way q-split -> 4 partial slabs, unique plain stores
//   kB GEMM-A (180 blk): K-chunk slabs (g1:3x256, c1_6:6x384, c1_7:6x256),
//      x = sum of 4 pool slabs during staging
//   kC GEMM-B (84 blk): g2 (3x256, x=sum3 g1p +tanh/bias),
//      c2 (4x384, x=sum6 c1p +tanh/bias)
//   kD final (64 blk): sums 3 g2p / 4 c2p slabs, refine chains, softmax, fc2
// Kernel boundaries provide cross-XCD coherence (same as proven baseline).
// ws floats: sentP 4x147456 | g1p 3x49152 | c1p 6x98304 | g2p 3x49152 |
//            c2p 4x49152   => ~6.7 MB.

typedef unsigned short u16;
typedef short short8 __attribute__((ext_vector_type(8)));
typedef float f32x4 __attribute__((ext_vector_type(4)));

#define PSLAB 147456  // pooling slab stride (64*2304)

__device__ __forceinline__ float bf2f(u16 h) {
    unsigned int u = ((unsigned int)h) << 16;
    float f;
    __builtin_memcpy(&f, &u, 4);
    return f;
}
__device__ __forceinline__ u16 f2bf(float f) {
    unsigned int u;
    __builtin_memcpy(&u, &f, 4);
    u = (u + 0x7fffu + ((u >> 16) & 1u)) >> 16;  // RNE
    return (u16)u;
}
__device__ __forceinline__ float sigm(float x) { return 1.0f / (1.0f + __expf(-x)); }

__device__ __forceinline__ float ldv(const void* p, long i, bool bf) {
    return bf ? bf2f(((const u16*)p)[i]) : ((const float*)p)[i];
}

// dtype detector: even-indexed u16s of fp32 N(0,1) data are mantissa bits
// (uniform -> ~6% in exponent window); of bf16 data they are values (~99%).
__device__ __forceinline__ bool detect_bf16(const u16* bert) {
    int hits = 0;
#pragma unroll
    for (int i = 0; i < 256; i += 2) {
        const int e = (bert[i] >> 7) & 0xFF;
        hits += (e >= 115 && e <= 130) ? 1 : 0;
    }
    return hits > 64;
}

// ---------------------------------------------------------------------------
// GEMM core: out(64 x Nout) = x(64 x Kchunk) @ B^T, 64x64 tile, K-chunk
// [k0, k0+kiters*128). UNIQUE writer per output address (per-chunk slab).
// NSUM: number of x partial slabs summed during staging (stride pslab).
// ACT: 1 -> x = tanh(xsum + bias[k % 768]).
// WMODE 0: W is [k][n] row-major, n-dim 768. WMODE 1: conv weights (O,I,3),
//   tap kb = kg/768 recomputed per 128-iter (768 % 128 == 0).
// mfma_f32_16x16x32_bf16; C/D col=lane&15, row=quad*4+reg.
// ---------------------------------------------------------------------------
template <int NSUM, int ACT, int WMODE>
__device__ __forceinline__ void gemm_core(
    const float* __restrict__ x, int xstride, int pslab,
    const void* __restrict__ bias, const void* __restrict__ W, bool bf,
    float* __restrict__ out, int ostride,
    int n0, int k0, int kiters, u16* As, u16* Bs)
{
    const int t = threadIdx.x;
    const int r = t >> 2;             // 0..63
    const int cseg = (t & 3) * 32;    // 0,32,64,96
    const int wave = t >> 6, lane = t & 63;
    const int lm = lane & 15, lq = lane >> 4;
    f32x4 acc[4] = {};

    for (int kk = 0; kk < kiters * 128; kk += 128) {
        const int kg = k0 + kk;
        // ---- stage x -> As (fp32 -> bf16), row stride 136 ----
        {
            const float* xp = x + (size_t)r * xstride + (kg + cseg);
            u16* dst = As + r * 136 + cseg;
#pragma unroll
            for (int i = 0; i < 8; ++i) {
                float4 v = ((const float4*)xp)[i];
#pragma unroll
                for (int sfx = 1; sfx < NSUM; ++sfx) {
                    float4 vv = ((const float4*)(xp + (size_t)sfx * pslab))[i];
                    v.x += vv.x; v.y += vv.y; v.z += vv.z; v.w += vv.w;
                }
                if (ACT) {
                    int kb = kg + cseg + i * 4;
                    if (kb >= 768) kb -= 768;   // K <= 1536, 4-aligned
                    v.x = tanhf(v.x + ldv(bias, kb, bf));
                    v.y = tanhf(v.y + ldv(bias, kb + 1, bf));
                    v.z = tanhf(v.z + ldv(bias, kb + 2, bf));
                    v.w = tanhf(v.w + ldv(bias, kb + 3, bf));
                }
                ((ushort4*)dst)[i] = make_ushort4(f2bf(v.x), f2bf(v.y), f2bf(v.z), f2bf(v.w));
            }
        }
        // ---- stage W -> Bs as [n][k], row stride 136 ----
        if (WMODE == 0) {
            const int p = t >> 2;             // k-pair: k = 2p, 2p+1
            const int nseg = (t & 3) * 16;    // 16 n's
            u16 q0[16], q1[16];
            if (bf) {
                const u16* w0 = (const u16*)W + (size_t)(kg + 2 * p) * 768 + n0 + nseg;
                ((uint4*)q0)[0] = ((const uint4*)w0)[0];
                ((uint4*)q0)[1] = ((const uint4*)w0)[1];
                ((uint4*)q1)[0] = ((const uint4*)(w0 + 768))[0];
                ((uint4*)q1)[1] = ((const uint4*)(w0 + 768))[1];
            } else {
                const float* w0 = (const float*)W + (size_t)(kg + 2 * p) * 768 + n0 + nseg;
#pragma unroll
                for (int e = 0; e < 4; ++e) {
                    float4 v0 = ((const float4*)w0)[e];
                    float4 v1 = ((const float4*)(w0 + 768))[e];
                    q0[4 * e] = f2bf(v0.x); q0[4 * e + 1] = f2bf(v0.y);
                    q0[4 * e + 2] = f2bf(v0.z); q0[4 * e + 3] = f2bf(v0.w);
                    q1[4 * e] = f2bf(v1.x); q1[4 * e + 1] = f2bf(v1.y);
                    q1[4 * e + 2] = f2bf(v1.z); q1[4 * e + 3] = f2bf(v1.w);
                }
            }
#pragma unroll
            for (int e = 0; e < 16; ++e)
                *(ushort2*)(Bs + (nseg + e) * 136 + 2 * p) = make_ushort2(q0[e], q1[e]);
        } else {
            const int kb = kg / 768;          // conv tap (const per 128-iter)
            const int i0c = kg - kb * 768;
            u16 tmp[32];
            if (bf) {
                const u16* wp = (const u16*)W + (size_t)(n0 + r) * 2304 + (size_t)(i0c + cseg) * 3 + kb;
#pragma unroll
                for (int j = 0; j < 32; ++j) tmp[j] = wp[j * 3];
            } else {
                const float* wp = (const float*)W + (size_t)(n0 + r) * 2304 + (size_t)(i0c + cseg) * 3 + kb;
#pragma unroll
                for (int j = 0; j < 32; ++j) tmp[j] = f2bf(wp[j * 3]);
            }
            u16* dst = Bs + r * 136 + cseg;
#pragma unroll
            for (int qq = 0; qq < 8; ++qq)
                ((ushort4*)dst)[qq] = ((ushort4*)tmp)[qq];
        }
        __syncthreads();
        const u16* ap = As + (wave * 16 + lm) * 136 + lq * 8;
        const u16* bp = Bs + lm * 136 + lq * 8;
#pragma unroll
        for (int ks = 0; ks < 4; ++ks) {
            short8 af = *(const short8*)(ap + ks * 32);
#pragma unroll
            for (int nf = 0; nf < 4; ++nf) {
                short8 bfr = *(const short8*)(bp + nf * 16 * 136 + ks * 32);
                acc[nf] = __builtin_amdgcn_mfma_f32_16x16x32_bf16(af, bfr, acc[nf], 0, 0, 0);
            }
        }
        __syncthreads();
    }
    // unique-writer plain stores (kernel boundary = coherence)
#pragma unroll
    for (int nf = 0; nf < 4; ++nf) {
#pragma unroll
        for (int rg = 0; rg < 4; ++rg) {
            const int row = wave * 16 + lq * 4 + rg;
            const int col = n0 + nf * 16 + lm;
            out[(size_t)row * ostride + col] = acc[nf][rg];
        }
    }
}

__device__ __forceinline__ float block_sum(float v, float* red) {
#pragma unroll
    for (int m = 1; m < 64; m <<= 1) v += __shfl_xor(v, m, 64);
    const int wave = threadIdx.x >> 6, lane = threadIdx.x & 63;
    if (lane == 0) red[wave] = v;
    __syncthreads();
    const float r = red[0] + red[1] + red[2] + red[3];
    __syncthreads();
    return r;
}

// ---------------------------------------------------------------------------
// kA: segment mean pool, 768 blocks = (b,si) x 4 q-splits -> 4 partial slabs
// ---------------------------------------------------------------------------
__global__ __launch_bounds__(256) void kA_pool(
    const void* __restrict__ bertv, const int* __restrict__ sb,
    float* __restrict__ sentP)
{
    const int u = blockIdx.x, t = threadIdx.x;
    const bool bf = detect_bf16((const u16*)bertv);
    const bool is64 = (sb[1] == 0);
    const int q = u & 3, v = u >> 2;       // v in [0,192)
    const int b = v / 3, si = v - 3 * (v / 3), s = 5 + si;
    const int i0 = b * 9 + s, i1 = i0 + 1;
    int st = is64 ? sb[2 * i0] : sb[i0];
    int en = is64 ? sb[2 * i1] : sb[i1];
    st = st < 0 ? 0 : (st > 511 ? 511 : st);
    en = en <= st ? st + 1 : (en > 512 ? 512 : en);
    const int n = en - st;
    const int r0 = st + (n * q) / 4;
    const int r1 = st + (n * (q + 1)) / 4;
    float a0 = 0.f, a1 = 0.f, a2 = 0.f;
    if (bf) {
        const u16* base = (const u16*)bertv + (size_t)b * 512 * 768;
        int l = r0;
        for (; l + 1 < r1; l += 2) {
            const u16* p0 = base + (size_t)l * 768;
            const u16* p1 = p0 + 768;
            a0 += bf2f(p0[t]) + bf2f(p1[t]);
            a1 += bf2f(p0[t + 256]) + bf2f(p1[t + 256]);
            a2 += bf2f(p0[t + 512]) + bf2f(p1[t + 512]);
        }
        if (l < r1) {
            const u16* p0 = base + (size_t)l * 768;
            a0 += bf2f(p0[t]);
            a1 += bf2f(p0[t + 256]);
            a2 += bf2f(p0[t + 512]);
        }
    } else {
        const float* base = (const float*)bertv + (size_t)b * 512 * 768;
        int l = r0;
        for (; l + 1 < r1; l += 2) {
            const float* p0 = base + (size_t)l * 768;
            const float* p1 = p0 + 768;
            a0 += p0[t] + p1[t];
            a1 += p0[t + 256] + p1[t + 256];
            a2 += p0[t + 512] + p1[t + 512];
        }
        if (l < r1) {
            const float* p0 = base + (size_t)l * 768;
            a0 += p0[t];
            a1 += p0[t + 256];
            a2 += p0[t + 512];
        }
    }
    const float inv = 1.0f / (float)n;
    float* o = sentP + (size_t)q * PSLAB + b * 2304 + si * 768;
    o[t] = a0 * inv;
    o[t + 256] = a1 * inv;
    o[t + 512] = a2 * inv;
}

// ---------------------------------------------------------------------------
// kB: GEMM-A, 180 blocks: g1 (36: nt*12 x jc*3 of 256), c1_6 (72: 12 x 6 of
// 384), c1_7 (72: 12 x 6 of 256). x = sum of 4 pool slabs.
// ---------------------------------------------------------------------------
__global__ __launch_bounds__(256) void kB_gemm_a(
    const float* __restrict__ sentP, const void* __restrict__ bertv,
    const void* __restrict__ gc1w, const void* __restrict__ c1w,
    float* __restrict__ g1p, float* __restrict__ c1p)
{
    __shared__ u16 As[64 * 136];
    __shared__ u16 Bs[64 * 136];
    const bool bf = detect_bf16((const u16*)bertv);
    const int u = blockIdx.x;
    if (u < 36) {
        const int nt = u / 3, jc = u % 3;
        gemm_core<4, 0, 0>(sentP + 1536, 2304, PSLAB, nullptr, gc1w, bf,
                           g1p + jc * 49152, 768, nt * 64, jc * 256, 2, As, Bs);
    } else if (u < 108) {
        const int v = u - 36, nt = v / 6, jc = v % 6;
        gemm_core<4, 0, 1>(sentP, 2304, PSLAB, nullptr, c1w, bf,
                           c1p + jc * 98304, 1536, nt * 64, jc * 384, 3, As, Bs);
    } else {
        const int v = u - 108, nt = v / 6, jc = v % 6;
        gemm_core<4, 0, 1>(sentP + 768, 2304, PSLAB, nullptr, c1w, bf,
                           c1p + jc * 98304 + 768, 1536, nt * 64, jc * 256, 2, As, Bs);
    }
}

// ---------------------------------------------------------------------------
// kC: GEMM-B, 84 blocks: g2 (36: 12 x 3 of 256, x=sum3 g1p tanh+gc1b),
// c2 (48: 12 x 4 of 384, x=sum6 c1p tanh+c1b).
// ---------------------------------------------------------------------------
__global__ __launch_bounds__(256) void kC_gemm_b(
    const float* __restrict__ g1p, const float* __restrict__ c1p,
    const void* __restrict__ bertv,
    const void* __restrict__ gc2w, const void* __restrict__ c2w,
    const void* __restrict__ gc1b, const void* __restrict__ c1b,
    float* __restrict__ g2p, float* __restrict__ c2p)
{
    __shared__ u16 As[64 * 136];
    __shared__ u16 Bs[64 * 136];
    const bool bf = detect_bf16((const u16*)bertv);
    const int u = blockIdx.x;
    if (u < 36) {
        const int nt = u / 3, jc = u % 3;
        gemm_core<3, 1, 0>(g1p, 768, 49152, gc1b, gc2w, bf,
                           g2p + jc * 49152, 768, nt * 64, jc * 256, 2, As, Bs);
    } else {
        const int v = u - 36, nt = v / 4, jc = v % 4;
        gemm_core<6, 1, 1>(c1p, 1536, 98304, c1b, c2w, bf,
                           c2p + jc * 49152, 768, nt * 64, jc * 384, 3, As, Bs);
    }
}

// ---------------------------------------------------------------------------
// kD: per-batch refine chains + softmax + fc2, 64 blocks
// ---------------------------------------------------------------------------
__global__ __launch_bounds__(256) void kD_final(
    const float* __restrict__ sentP, const float* __restrict__ g2p,
    const float* __restrict__ c2p, const void* __restrict__ bertv,
    const void* __restrict__ gc2b, const void* __restrict__ c2b,
    const void* __restrict__ lng, const void* __restrict__ lnb,
    const void* __restrict__ target, const void* __restrict__ fc2w,
    const void* __restrict__ fc2b, void* __restrict__ outp)
{
    __shared__ float red[4];
    const bool bf = detect_bf16((const u16*)bertv);
    const int t = threadIdx.x, b = blockIdx.x;
    float s_[3], g_[3], bb_[3];
    const float* srow = sentP + b * 2304 + 1536;  // sent7 slab 0
#pragma unroll
    for (int i = 0; i < 3; ++i) {
        const int d = t + 256 * i;
        s_[i] = srow[d] + srow[d + PSLAB] + srow[d + 2 * PSLAB] + srow[d + 3 * PSLAB];
        g_[i] = ldv(lng, d, bf);
        bb_[i] = ldv(lnb, d, bf);
    }

    auto refine2 = [&](float* yv) {
#pragma unroll
        for (int it = 0; it < 2; ++it) {
            const float c = block_sum(yv[0] * s_[0] + yv[1] * s_[1] + yv[2] * s_[2], red);
            float tt[3], sm = 0.0f, sq = 0.0f;
#pragma unroll
            for (int i = 0; i < 3; ++i) {
                tt[i] = sigm(c * s_[i]);
                sm += tt[i];
                sq += tt[i] * tt[i];
            }
            const float m = block_sum(sm, red) * (1.0f / 768.0f);
            const float q = block_sum(sq, red) * (1.0f / 768.0f);
            const float inv = rsqrtf(fmaxf(q - m * m, 0.0f) + 1e-5f);
#pragma unroll
            for (int i = 0; i < 3; ++i)
                yv[i] = 0.5f * ((tt[i] - m) * inv * g_[i] + bb_[i]) + s_[i];
        }
    };

    float a3[3], a4[3], a5[3], y[3];
#pragma unroll
    for (int i = 0; i < 3; ++i) {
        const int d = t + 256 * i;
        const float gs = g2p[b * 768 + d] + g2p[49152 + b * 768 + d] + g2p[98304 + b * 768 + d];
        y[i] = tanhf(gs + ldv(gc2b, d, bf));
    }
    refine2(y);
    a3[0] = y[0]; a3[1] = y[1]; a3[2] = y[2];
#pragma unroll
    for (int i = 0; i < 3; ++i) {
        const int d = t + 256 * i;
        const float cs = c2p[b * 768 + d] + c2p[49152 + b * 768 + d]
                       + c2p[98304 + b * 768 + d] + c2p[147456 + b * 768 + d];
        y[i] = tanhf(cs + ldv(c2b, d, bf));
    }
    refine2(y);
    a4[0] = y[0]; a4[1] = y[1]; a4[2] = y[2];
    const float ss = block_sum(s_[0] * s_[0] + s_[1] * s_[1] + s_[2] * s_[2], red);
#pragma unroll
    for (int i = 0; i < 3; ++i) y[i] = sigm(ss * s_[i]);
    refine2(y);
    a5[0] = y[0]; a5[1] = y[1]; a5[2] = y[2];

    float tg[3];
#pragma unroll
    for (int i = 0; i < 3; ++i) tg[i] = ldv(target, t + 256 * i, bf);  // target[0]
    const float u0 = block_sum(a3[0] * tg[0] + a3[1] * tg[1] + a3[2] * tg[2], red);
    const float u1 = block_sum(a4[0] * tg[0] + a4[1] * tg[1] + a4[2] * tg[2], red);
    const float u2 = block_sum(a5[0] * tg[0] + a5[1] * tg[1] + a5[2] * tg[2], red);
    const float mx = fmaxf(u0, fmaxf(u1, u2));
    const float e0 = __expf(u0 - mx), e1 = __expf(u1 - mx), e2 = __expf(u2 - mx);
    const float es = e0 + e1 + e2;
    const float w0 = e0 / es, w1 = e1 / es, w2 = e2 / es;

    float p0 = 0.0f, p1 = 0.0f, p2 = 0.0f;
#pragma unroll
    for (int i = 0; i < 3; ++i) {
        const int d = t + 256 * i;
        const float va = w0 * a3[i], vb = w1 * a4[i], vc = w2 * a5[i];
        p0 += va * ldv(fc2w, d * 3 + 0, bf) + vb * ldv(fc2w, (768 + d) * 3 + 0, bf) + vc * ldv(fc2w, (1536 + d) * 3 + 0, bf);
        p1 += va * ldv(fc2w, d * 3 + 1, bf) + vb * ldv(fc2w, (768 + d) * 3 + 1, bf) + vc * ldv(fc2w, (1536 + d) * 3 + 1, bf);
        p2 += va * ldv(fc2w, d * 3 + 2, bf) + vb * ldv(fc2w, (768 + d) * 3 + 2, bf) + vc * ldv(fc2w, (1536 + d) * 3 + 2, bf);
    }
    p0 = block_sum(p0, red);
    p1 = block_sum(p1, red);
    p2 = block_sum(p2, red);
    if (t == 0) {
        const float o0 = p0 + ldv(fc2b, 0, bf);
        const float o1 = p1 + ldv(fc2b, 1, bf);
        const float o2 = p2 + ldv(fc2b, 2, bf);
        if (bf) {
            ((u16*)outp)[b * 3 + 0] = f2bf(o0);
            ((u16*)outp)[b * 3 + 1] = f2bf(o1);
            ((u16*)outp)[b * 3 + 2] = f2bf(o2);
        } else {
            ((float*)outp)[b * 3 + 0] = o0;
            ((float*)outp)[b * 3 + 1] = o1;
            ((float*)outp)[b * 3 + 2] = o2;
        }
    }
}

extern "C" void kernel_launch(void* const* d_in, const int* in_sizes, int n_in,
                              void* d_out, int out_size, void* d_ws, size_t ws_size,
                              hipStream_t stream) {
    const void* bert   = d_in[0];
    const void* target = d_in[1];
    const void* gc1w   = d_in[2];
    const void* gc1b   = d_in[3];
    const void* gc2w   = d_in[4];
    const void* gc2b   = d_in[5];
    const void* c1w    = d_in[6];
    const void* c1b    = d_in[7];
    const void* c2w    = d_in[8];
    const void* c2b    = d_in[9];
    const void* lng    = d_in[10];
    const void* lnb    = d_in[11];
    const void* fc2w   = d_in[12];
    const void* fc2b   = d_in[13];
    const int*  sb     = (const int*)d_in[14];

    float* sentP = (float*)d_ws;           // 4 x 147456
    float* g1p   = sentP + 4 * PSLAB;      // 3 x 49152
    float* c1p   = g1p + 147456;           // 6 x 98304
    float* g2p   = c1p + 589824;           // 3 x 49152
    float* c2p   = g2p + 147456;           // 4 x 49152

    kA_pool<<<768, 256, 0, stream>>>(bert, sb, sentP);
    kB_gemm_a<<<180, 256, 0, stream>>>(sentP, bert, gc1w, c1w, g1p, c1p);
    kC_gemm_b<<<84, 256, 0, stream>>>(g1p, c1p, bert, gc2w, c2w, gc1b, c1b, g2p, c2p);
    kD_final<<<64, 256, 0, stream>>>(sentP, g2p, c2p, bert, gc2b, c2b, lng, lnb,
                                     target, fc2w, fc2b, d_out);
}

// Round 5
// 244.996 us; speedup vs baseline: 1.8902x; 1.0877x over previous
//
#include <hip/hip_runtime.h>

// Problem: B=64, L=512, D=768, S=8, HOP=3, LAMB=0.5
// Output depends only on sentence segments s in {5,6,7}.
// R9: revert to the R4 champion structure (224us; split kernels, 216/108
// GEMM blocks, fixed 2x128 K-loops, atomicAdd outputs) with two proven,
// mechanism-clear deltas:
//   1. k0_zero eliminated: pool writes 4 unique slabs (R5/R8-proven);
//      GEMM-A sums the slabs during x-staging (XMODE 2, R5-proven);
//      accs zeroing folded into kA (disjoint region, kernel-boundary
//      ordering to the atomicAdd consumers).
//   2. kD rewritten wave-per-batch (16 blocks x 4 waves): reductions are
//      6 shfl_xor instead of block-wide LDS+syncthreads round-trips.
// 4 dispatches: kA pool+zero (768) | kB GEMM-A (216) | kC GEMM-B (108) |
// kD final (16). No memset, no flag kernel (dtype re-detected per block).
// ws floats: sentP 4x147456 | accs 245760 (g1 49152 | c1 98304 | g2 49152 |
// c2 49152)  => ~3.3 MB.

typedef unsigned short u16;
typedef short short8 __attribute__((ext_vector_type(8)));
typedef float f32x4 __attribute__((ext_vector_type(4)));

#define PSLAB 147456  // pooling slab stride (64*2304)

__device__ __forceinline__ float bf2f(u16 h) {
    unsigned int u = ((unsigned int)h) << 16;
    float f;
    __builtin_memcpy(&f, &u, 4);
    return f;
}
__device__ __forceinline__ u16 f2bf(float f) {
    unsigned int u;
    __builtin_memcpy(&u, &f, 4);
    u = (u + 0x7fffu + ((u >> 16) & 1u)) >> 16;  // RNE
    return (u16)u;
}
__device__ __forceinline__ float sigm(float x) { return 1.0f / (1.0f + __expf(-x)); }

__device__ __forceinline__ float ldv(const void* p, long i, bool bf) {
    return bf ? bf2f(((const u16*)p)[i]) : ((const float*)p)[i];
}

// dtype detector: even-indexed u16s of fp32 N(0,1) data are mantissa bits
// (uniform -> ~6% in exponent window); of bf16 data they are values (~99%).
__device__ __forceinline__ bool detect_bf16(const u16* bert) {
    int hits = 0;
#pragma unroll
    for (int i = 0; i < 256; i += 2) {
        const int e = (bert[i] >> 7) & 0xFF;
        hits += (e >= 115 && e <= 130) ? 1 : 0;
    }
    return hits > 64;
}

// ---------------------------------------------------------------------------
// GEMM core (R4 champion): out(64 x Nout) += x(64 x K) @ B^T, 64x64 tile,
// K-chunk [k0, k0+256) as 2x128 iters. Output accumulated via atomicAdd.
// XMODE 0: x raw fp32. XMODE 1: x = tanh(raw + bias[k % 768]).
// XMODE 2: x = sum of 4 partial slabs at stride pslab (pooling partials).
// WMODE 0: W is [k][n] row-major, n-dim 768. WMODE 1: conv weights (O,I,3),
//   tap kb = kg/768 (constant within a 128-iter since 768 = 6*128).
// mfma_f32_16x16x32_bf16; C/D col=lane&15, row=quad*4+reg.
// ---------------------------------------------------------------------------
template <int XMODE, int WMODE>
__device__ __forceinline__ void gemm_core(
    const float* __restrict__ x, int xstride, int pslab,
    const void* __restrict__ bias, const void* __restrict__ W, bool bf,
    float* __restrict__ out, int ostride,
    int n0, int k0, u16* As, u16* Bs)
{
    const int t = threadIdx.x;
    const int r = t >> 2;             // 0..63
    const int cseg = (t & 3) * 32;    // 0,32,64,96
    const int wave = t >> 6, lane = t & 63;
    const int lm = lane & 15, lq = lane >> 4;
    f32x4 acc[4] = {};

    for (int kk = 0; kk < 256; kk += 128) {
        const int kg = k0 + kk;
        // ---- stage x -> As (fp32 -> bf16), row stride 136 ----
        {
            const float* xp = x + (size_t)r * xstride + (kg + cseg);
            u16* dst = As + r * 136 + cseg;
#pragma unroll
            for (int i = 0; i < 8; ++i) {
                float4 v = ((const float4*)xp)[i];
                if (XMODE == 2) {
                    float4 v1 = ((const float4*)(xp + pslab))[i];
                    float4 v2 = ((const float4*)(xp + 2 * pslab))[i];
                    float4 v3 = ((const float4*)(xp + 3 * pslab))[i];
                    v.x += v1.x + v2.x + v3.x;
                    v.y += v1.y + v2.y + v3.y;
                    v.z += v1.z + v2.z + v3.z;
                    v.w += v1.w + v2.w + v3.w;
                }
                if (XMODE == 1) {
                    int kb = kg + cseg + i * 4;
                    if (kb >= 768) kb -= 768;   // K <= 1536, 4-aligned
                    v.x = tanhf(v.x + ldv(bias, kb, bf));
                    v.y = tanhf(v.y + ldv(bias, kb + 1, bf));
                    v.z = tanhf(v.z + ldv(bias, kb + 2, bf));
                    v.w = tanhf(v.w + ldv(bias, kb + 3, bf));
                }
                ((ushort4*)dst)[i] = make_ushort4(f2bf(v.x), f2bf(v.y), f2bf(v.z), f2bf(v.w));
            }
        }
        // ---- stage W -> Bs as [n][k], row stride 136 ----
        if (WMODE == 0) {
            const int p = t >> 2;             // k-pair: k = 2p, 2p+1
            const int nseg = (t & 3) * 16;    // 16 n's
            u16 q0[16], q1[16];
            if (bf) {
                const u16* w0 = (const u16*)W + (size_t)(kg + 2 * p) * 768 + n0 + nseg;
                ((uint4*)q0)[0] = ((const uint4*)w0)[0];
                ((uint4*)q0)[1] = ((const uint4*)w0)[1];
                ((uint4*)q1)[0] = ((const uint4*)(w0 + 768))[0];
                ((uint4*)q1)[1] = ((const uint4*)(w0 + 768))[1];
            } else {
                const float* w0 = (const float*)W + (size_t)(kg + 2 * p) * 768 + n0 + nseg;
#pragma unroll
                for (int e = 0; e < 4; ++e) {
                    float4 v0 = ((const float4*)w0)[e];
                    float4 v1 = ((const float4*)(w0 + 768))[e];
                    q0[4 * e] = f2bf(v0.x); q0[4 * e + 1] = f2bf(v0.y);
                    q0[4 * e + 2] = f2bf(v0.z); q0[4 * e + 3] = f2bf(v0.w);
                    q1[4 * e] = f2bf(v1.x); q1[4 * e + 1] = f2bf(v1.y);
                    q1[4 * e + 2] = f2bf(v1.z); q1[4 * e + 3] = f2bf(v1.w);
                }
            }
#pragma unroll
            for (int e = 0; e < 16; ++e)
                *(ushort2*)(Bs + (nseg + e) * 136 + 2 * p) = make_ushort2(q0[e], q1[e]);
        } else {
            const int kb = kg / 768;          // conv tap (const per 128-iter)
            const int i0c = kg - kb * 768;
            u16 tmp[32];
            if (bf) {
                const u16* wp = (const u16*)W + (size_t)(n0 + r) * 2304 + (size_t)(i0c + cseg) * 3 + kb;
#pragma unroll
                for (int j = 0; j < 32; ++j) tmp[j] = wp[j * 3];
            } else {
                const float* wp = (const float*)W + (size_t)(n0 + r) * 2304 + (size_t)(i0c + cseg) * 3 + kb;
#pragma unroll
                for (int j = 0; j < 32; ++j) tmp[j] = f2bf(wp[j * 3]);
            }
            u16* dst = Bs + r * 136 + cseg;
#pragma unroll
            for (int qq = 0; qq < 8; ++qq)
                ((ushort4*)dst)[qq] = ((ushort4*)tmp)[qq];
        }
        __syncthreads();
        const u16* ap = As + (wave * 16 + lm) * 136 + lq * 8;
        const u16* bp = Bs + lm * 136 + lq * 8;
#pragma unroll
        for (int ks = 0; ks < 4; ++ks) {
            short8 af = *(const short8*)(ap + ks * 32);
#pragma unroll
            for (int nf = 0; nf < 4; ++nf) {
                short8 bfr = *(const short8*)(bp + nf * 16 * 136 + ks * 32);
                acc[nf] = __builtin_amdgcn_mfma_f32_16x16x32_bf16(af, bfr, acc[nf], 0, 0, 0);
            }
        }
        __syncthreads();
    }
#pragma unroll
    for (int nf = 0; nf < 4; ++nf) {
#pragma unroll
        for (int rg = 0; rg < 4; ++rg) {
            const int row = wave * 16 + lq * 4 + rg;
            const int col = n0 + nf * 16 + lm;
            atomicAdd(out + (size_t)row * ostride + col, acc[nf][rg]);
        }
    }
}

// ---------------------------------------------------------------------------
// kA: segment mean pool -> 4 unique slabs (768 blocks = (b,si) x 4 q-splits)
// + zero the accs region (80 float4 per block; disjoint from pool outputs,
// ordered to consumers by the kernel boundary).
// ---------------------------------------------------------------------------
__global__ __launch_bounds__(256) void kA_pool(
    const void* __restrict__ bertv, const int* __restrict__ sb,
    float* __restrict__ sentP, float* __restrict__ accs)
{
    const int u = blockIdx.x, t = threadIdx.x;
    if (t < 80)
        ((float4*)accs)[u * 80 + t] = make_float4(0.f, 0.f, 0.f, 0.f);
    const bool bf = detect_bf16((const u16*)bertv);
    const bool is64 = (sb[1] == 0);
    const int q = u & 3, v = u >> 2;       // v in [0,192)
    const int b = v / 3, si = v - 3 * (v / 3), s = 5 + si;
    const int i0 = b * 9 + s, i1 = i0 + 1;
    int st = is64 ? sb[2 * i0] : sb[i0];
    int en = is64 ? sb[2 * i1] : sb[i1];
    st = st < 0 ? 0 : (st > 511 ? 511 : st);
    en = en <= st ? st + 1 : (en > 512 ? 512 : en);
    const int n = en - st;
    const int r0 = st + (n * q) / 4;
    const int r1 = st + (n * (q + 1)) / 4;
    float a0 = 0.f, a1 = 0.f, a2 = 0.f;
    if (bf) {
        const u16* base = (const u16*)bertv + (size_t)b * 512 * 768;
        int l = r0;
        for (; l + 1 < r1; l += 2) {
            const u16* p0 = base + (size_t)l * 768;
            const u16* p1 = p0 + 768;
            a0 += bf2f(p0[t]) + bf2f(p1[t]);
            a1 += bf2f(p0[t + 256]) + bf2f(p1[t + 256]);
            a2 += bf2f(p0[t + 512]) + bf2f(p1[t + 512]);
        }
        if (l < r1) {
            const u16* p0 = base + (size_t)l * 768;
            a0 += bf2f(p0[t]);
            a1 += bf2f(p0[t + 256]);
            a2 += bf2f(p0[t + 512]);
        }
    } else {
        const float* base = (const float*)bertv + (size_t)b * 512 * 768;
        int l = r0;
        for (; l + 1 < r1; l += 2) {
            const float* p0 = base + (size_t)l * 768;
            const float* p1 = p0 + 768;
            a0 += p0[t] + p1[t];
            a1 += p0[t + 256] + p1[t + 256];
            a2 += p0[t + 512] + p1[t + 512];
        }
        if (l < r1) {
            const float* p0 = base + (size_t)l * 768;
            a0 += p0[t];
            a1 += p0[t + 256];
            a2 += p0[t + 512];
        }
    }
    const float inv = 1.0f / (float)n;
    float* o = sentP + (size_t)q * PSLAB + b * 2304 + si * 768;
    o[t] = a0 * inv;
    o[t + 256] = a1 * inv;
    o[t + 512] = a2 * inv;
}

// ---------------------------------------------------------------------------
// kB: GEMM-A (R4 shapes, 216 blocks): g1 = sent7 @ gc1_w (36);
// c1_6 (108: x=[s5|s6|s7] K=2304); c1_7 (72: x=[s6|s7] K=1536).
// x = sum of 4 pool slabs (XMODE 2). atomicAdd into zeroed accs.
// ---------------------------------------------------------------------------
__global__ __launch_bounds__(256) void kB_gemm_a(
    const float* __restrict__ sentP, const void* __restrict__ bertv,
    const void* __restrict__ gc1w, const void* __restrict__ c1w,
    float* __restrict__ g1acc, float* __restrict__ c1acc)
{
    __shared__ u16 As[64 * 136];
    __shared__ u16 Bs[64 * 136];
    const bool bf = detect_bf16((const u16*)bertv);
    const int u = blockIdx.x;
    if (u < 36) {
        gemm_core<2, 0>(sentP + 1536, 2304, PSLAB, nullptr, gc1w, bf, g1acc, 768,
                        (u / 3) * 64, (u % 3) * 256, As, Bs);
    } else if (u < 144) {
        const int v = u - 36;
        gemm_core<2, 1>(sentP, 2304, PSLAB, nullptr, c1w, bf, c1acc, 1536,
                        (v / 9) * 64, (v % 9) * 256, As, Bs);
    } else {
        const int v = u - 144;
        gemm_core<2, 1>(sentP + 768, 2304, PSLAB, nullptr, c1w, bf, c1acc + 768, 1536,
                        (v / 6) * 64, (v % 6) * 256, As, Bs);
    }
}

// ---------------------------------------------------------------------------
// kC: GEMM-B (R4 shapes, 108 blocks): g2 = tanh(g1+gc1b) @ gc2_w (36);
// c2 = tanh(c1+c1b) @ W2 (72). atomicAdd into zeroed accs.
// ---------------------------------------------------------------------------
__global__ __launch_bounds__(256) void kC_gemm_b(
    const float* __restrict__ g1acc, const float* __restrict__ c1acc,
    const void* __restrict__ bertv,
    const void* __restrict__ gc2w, const void* __restrict__ c2w,
    const void* __restrict__ gc1b, const void* __restrict__ c1b,
    float* __restrict__ g2acc, float* __restrict__ c2acc)
{
    __shared__ u16 As[64 * 136];
    __shared__ u16 Bs[64 * 136];
    const bool bf = detect_bf16((const u16*)bertv);
    const int u = blockIdx.x;
    if (u < 36) {
        gemm_core<1, 0>(g1acc, 768, 0, gc1b, gc2w, bf, g2acc, 768,
                        (u / 3) * 64, (u % 3) * 256, As, Bs);
    } else {
        const int v = u - 36;
        gemm_core<1, 1>(c1acc, 1536, 0, c1b, c2w, bf, c2acc, 768,
                        (v / 6) * 64, (v % 6) * 256, As, Bs);
    }
}

// ---------------------------------------------------------------------------
// kD: refine chains + softmax + fc2. 16 blocks x 4 waves, ONE BATCH PER
// WAVE: 768 elems = 12/lane; every reduction is 6 shfl_xor (no LDS, no
// __syncthreads) instead of a block-wide reduction round-trip.
// ---------------------------------------------------------------------------
__device__ __forceinline__ float wsum(float v) {
#pragma unroll
    for (int m = 1; m < 64; m <<= 1) v += __shfl_xor(v, m, 64);
    return v;
}

__global__ __launch_bounds__(256) void kD_final(
    const float* __restrict__ sentP, const float* __restrict__ g2acc,
    const float* __restrict__ c2acc, const void* __restrict__ bertv,
    const void* __restrict__ gc2b, const void* __restrict__ c2b,
    const void* __restrict__ lng, const void* __restrict__ lnb,
    const void* __restrict__ target, const void* __restrict__ fc2w,
    const void* __restrict__ fc2b, void* __restrict__ outp)
{
    const bool bf = detect_bf16((const u16*)bertv);
    const int t = threadIdx.x, wave = t >> 6, lane = t & 63;
    const int b = blockIdx.x * 4 + wave;   // 16 blocks x 4 waves = 64 batches

    float s_[12], g_[12], bb_[12];
    const float* srow = sentP + b * 2304 + 1536;  // sent7 slab 0
#pragma unroll
    for (int i = 0; i < 12; ++i) {
        const int d = lane + 64 * i;
        s_[i] = srow[d] + srow[d + PSLAB] + srow[d + 2 * PSLAB] + srow[d + 3 * PSLAB];
        g_[i] = ldv(lng, d, bf);
        bb_[i] = ldv(lnb, d, bf);
    }

    auto refine2 = [&](float* yv) {
#pragma unroll
        for (int it = 0; it < 2; ++it) {
            float cacc = 0.f;
#pragma unroll
            for (int i = 0; i < 12; ++i) cacc += yv[i] * s_[i];
            const float c = wsum(cacc);
            float tt[12], sm = 0.0f, sq = 0.0f;
#pragma unroll
            for (int i = 0; i < 12; ++i) {
                tt[i] = sigm(c * s_[i]);
                sm += tt[i];
                sq += tt[i] * tt[i];
            }
            const float m = wsum(sm) * (1.0f / 768.0f);
            const float q = wsum(sq) * (1.0f / 768.0f);
            const float inv = rsqrtf(fmaxf(q - m * m, 0.0f) + 1e-5f);
#pragma unroll
            for (int i = 0; i < 12; ++i)
                yv[i] = 0.5f * ((tt[i] - m) * inv * g_[i] + bb_[i]) + s_[i];
        }
    };

    float a3[12], a4[12], a5[12], y[12];
#pragma unroll
    for (int i = 0; i < 12; ++i) {
        const int d = lane + 64 * i;
        y[i] = tanhf(g2acc[b * 768 + d] + ldv(gc2b, d, bf));
    }
    refine2(y);
#pragma unroll
    for (int i = 0; i < 12; ++i) a3[i] = y[i];
#pragma unroll
    for (int i = 0; i < 12; ++i) {
        const int d = lane + 64 * i;
        y[i] = tanhf(c2acc[b * 768 + d] + ldv(c2b, d, bf));
    }
    refine2(y);
#pragma unroll
    for (int i = 0; i < 12; ++i) a4[i] = y[i];
    float ssacc = 0.f;
#pragma unroll
    for (int i = 0; i < 12; ++i) ssacc += s_[i] * s_[i];
    const float ss = wsum(ssacc);
#pragma unroll
    for (int i = 0; i < 12; ++i) y[i] = sigm(ss * s_[i]);
    refine2(y);
#pragma unroll
    for (int i = 0; i < 12; ++i) a5[i] = y[i];

    float d0 = 0.f, d1 = 0.f, d2 = 0.f;
#pragma unroll
    for (int i = 0; i < 12; ++i) {
        const float tg = ldv(target, lane + 64 * i, bf);  // target[0]
        d0 += a3[i] * tg;
        d1 += a4[i] * tg;
        d2 += a5[i] * tg;
    }
    const float u0 = wsum(d0), u1 = wsum(d1), u2 = wsum(d2);
    const float mx = fmaxf(u0, fmaxf(u1, u2));
    const float e0 = __expf(u0 - mx), e1 = __expf(u1 - mx), e2 = __expf(u2 - mx);
    const float es = e0 + e1 + e2;
    const float w0 = e0 / es, w1 = e1 / es, w2 = e2 / es;

    float p0 = 0.0f, p1 = 0.0f, p2 = 0.0f;
#pragma unroll
    for (int i = 0; i < 12; ++i) {
        const int d = lane + 64 * i;
        const float va = w0 * a3[i], vb = w1 * a4[i], vc = w2 * a5[i];
        p0 += va * ldv(fc2w, d * 3 + 0, bf) + vb * ldv(fc2w, (768 + d) * 3 + 0, bf) + vc * ldv(fc2w, (1536 + d) * 3 + 0, bf);
        p1 += va * ldv(fc2w, d * 3 + 1, bf) + vb * ldv(fc2w, (768 + d) * 3 + 1, bf) + vc * ldv(fc2w, (1536 + d) * 3 + 1, bf);
        p2 += va * ldv(fc2w, d * 3 + 2, bf) + vb * ldv(fc2w, (768 + d) * 3 + 2, bf) + vc * ldv(fc2w, (1536 + d) * 3 + 2, bf);
    }
    p0 = wsum(p0);
    p1 = wsum(p1);
    p2 = wsum(p2);
    if (lane == 0) {
        const float o0 = p0 + ldv(fc2b, 0, bf);
        const float o1 = p1 + ldv(fc2b, 1, bf);
        const float o2 = p2 + ldv(fc2b, 2, bf);
        if (bf) {
            ((u16*)outp)[b * 3 + 0] = f2bf(o0);
            ((u16*)outp)[b * 3 + 1] = f2bf(o1);
            ((u16*)outp)[b * 3 + 2] = f2bf(o2);
        } else {
            ((float*)outp)[b * 3 + 0] = o0;
            ((float*)outp)[b * 3 + 1] = o1;
            ((float*)outp)[b * 3 + 2] = o2;
        }
    }
}

extern "C" void kernel_launch(void* const* d_in, const int* in_sizes, int n_in,
                              void* d_out, int out_size, void* d_ws, size_t ws_size,
                              hipStream_t stream) {
    const void* bert   = d_in[0];
    const void* target = d_in[1];
    const void* gc1w   = d_in[2];
    const void* gc1b   = d_in[3];
    const void* gc2w   = d_in[4];
    const void* gc2b   = d_in[5];
    const void* c1w    = d_in[6];
    const void* c1b    = d_in[7];
    const void* c2w    = d_in[8];
    const void* c2b    = d_in[9];
    const void* lng    = d_in[10];
    const void* lnb    = d_in[11];
    const void* fc2w   = d_in[12];
    const void* fc2b   = d_in[13];
    const int*  sb     = (const int*)d_in[14];

    float* sentP = (float*)d_ws;           // 4 x 147456
    float* accs  = sentP + 4 * PSLAB;      // 245760 floats
    float* g1acc = accs;                   // 64 x 768
    float* c1acc = accs + 49152;           // 64 x 1536 [c1_6 | c1_7]
    float* g2acc = c1acc + 98304;          // 64 x 768
    float* c2acc = g2acc + 49152;          // 64 x 768

    kA_pool<<<768, 256, 0, stream>>>(bert, sb, sentP, accs);
    kB_gemm_a<<<216, 256, 0, stream>>>(sentP, bert, gc1w, c1w, g1acc, c1acc);
    kC_gemm_b<<<108, 256, 0, stream>>>(g1acc, c1acc, bert, gc2w, c2w, gc1b, c1b, g2acc, c2acc);
    kD_final<<<16, 256, 0, stream>>>(sentP, g2acc, c2acc, bert, gc2b, c2b, lng, lnb,
                                     target, fc2w, fc2b, d_out);
}

// Round 6
// 218.586 us; speedup vs baseline: 2.1186x; 1.1208x over previous
//
#include <hip/hip_runtime.h>

// Problem: B=64, L=512, D=768, S=8, HOP=3, LAMB=0.5
// Output depends only on sentence segments s in {5,6,7}.
// R10 = R4 champion (224.5us) with EXACTLY ONE structural change:
//   {k0_zero + atomicAdd row-split pooling} -> column-split pooling kA:
//   block (b,si,cq) owns cols [cq*192,(cq+1)*192) of sentF[b][si]; 4 waves
//   split the segment rows; LDS[4][192] reduce; UNIQUE plain stores cover
//   every sentF element => no sentF zeroing, no atomics, k0 deleted.
//   kA also zeroes accs (80 float4/block, disjoint; consumers are k2/k3
//   beyond the kernel boundary) and writes flagp (as k1 did).
// k2/k3/k4 + gemm_core are byte-identical to the R4 champion.
// ws (fp32): sentF 64x2304 | accs g1(64x768) c1(64x1536) g2(64x768)
// c2(64x768) | flag(1)  => ~1.54 MB.

typedef unsigned short u16;
typedef short short8 __attribute__((ext_vector_type(8)));
typedef float f32x4 __attribute__((ext_vector_type(4)));

__device__ __forceinline__ float bf2f(u16 h) {
    unsigned int u = ((unsigned int)h) << 16;
    float f;
    __builtin_memcpy(&f, &u, 4);
    return f;
}
__device__ __forceinline__ u16 f2bf(float f) {
    unsigned int u;
    __builtin_memcpy(&u, &f, 4);
    u = (u + 0x7fffu + ((u >> 16) & 1u)) >> 16;  // RNE
    return (u16)u;
}
__device__ __forceinline__ float sigm(float x) { return 1.0f / (1.0f + __expf(-x)); }

// generic scalar load: bf16 bits or fp32
__device__ __forceinline__ float ldv(const void* p, long i, bool bf) {
    return bf ? bf2f(((const u16*)p)[i]) : ((const float*)p)[i];
}

// dtype detector: even-indexed u16s of fp32 N(0,1) data are mantissa bits
// (uniform -> ~6% in exponent window); of bf16 data they are values (~99%).
__device__ __forceinline__ bool detect_bf16(const u16* bert) {
    int hits = 0;
#pragma unroll
    for (int i = 0; i < 256; i += 2) {
        const int e = (bert[i] >> 7) & 0xFF;
        hits += (e >= 115 && e <= 130) ? 1 : 0;
    }
    return hits > 64;
}

// ---------------------------------------------------------------------------
// kA: column-split segment mean pool (768 blocks = (b,si) x 4 col-quarters).
// Wave w accumulates rows [st + n*w/4, st + n*(w+1)/4) over its 192 cols
// (3 per lane), LDS-reduce across waves, unique stores. Also zeroes accs
// (80 float4 per block) and writes the dtype flag.
// ---------------------------------------------------------------------------
__global__ __launch_bounds__(256) void kA_pool(
    const void* __restrict__ bertv, const int* __restrict__ sb,
    float* __restrict__ sentF, float* __restrict__ accs, float* __restrict__ flagp)
{
    __shared__ float red[4][192];
    const int u = blockIdx.x, t = threadIdx.x;
    // zero the GEMM accumulators: 768 blocks x 80 float4 = 245760 floats
    if (t < 80)
        ((float4*)accs)[u * 80 + t] = make_float4(0.f, 0.f, 0.f, 0.f);
    const bool bf = detect_bf16((const u16*)bertv);
    const bool is64 = (sb[1] == 0);  // int64 low/high interleave (LE)
    if (u == 0 && t == 0) flagp[0] = bf ? 1.0f : 0.0f;

    const int cq = u & 3, v = u >> 2;      // v in [0,192)
    const int b = v / 3, si = v - 3 * (v / 3), s = 5 + si;
    const int i0 = b * 9 + s, i1 = i0 + 1;
    int st = is64 ? sb[2 * i0] : sb[i0];
    int en = is64 ? sb[2 * i1] : sb[i1];
    st = st < 0 ? 0 : (st > 511 ? 511 : st);
    en = en <= st ? st + 1 : (en > 512 ? 512 : en);
    const int n = en - st;

    const int wave = t >> 6, lane = t & 63;
    const int r0 = st + (n * wave) / 4;
    const int r1 = st + (n * (wave + 1)) / 4;
    const int col0 = cq * 192;

    float a0 = 0.f, a1 = 0.f, a2 = 0.f;
    if (bf) {
        const u16* base = (const u16*)bertv + (size_t)b * 512 * 768 + col0;
        int l = r0;
        for (; l + 1 < r1; l += 2) {
            const u16* p0 = base + (size_t)l * 768;
            const u16* p1 = p0 + 768;
            a0 += bf2f(p0[lane]) + bf2f(p1[lane]);
            a1 += bf2f(p0[lane + 64]) + bf2f(p1[lane + 64]);
            a2 += bf2f(p0[lane + 128]) + bf2f(p1[lane + 128]);
        }
        if (l < r1) {
            const u16* p0 = base + (size_t)l * 768;
            a0 += bf2f(p0[lane]);
            a1 += bf2f(p0[lane + 64]);
            a2 += bf2f(p0[lane + 128]);
        }
    } else {
        const float* base = (const float*)bertv + (size_t)b * 512 * 768 + col0;
        int l = r0;
        for (; l + 1 < r1; l += 2) {
            const float* p0 = base + (size_t)l * 768;
            const float* p1 = p0 + 768;
            a0 += p0[lane] + p1[lane];
            a1 += p0[lane + 64] + p1[lane + 64];
            a2 += p0[lane + 128] + p1[lane + 128];
        }
        if (l < r1) {
            const float* p0 = base + (size_t)l * 768;
            a0 += p0[lane];
            a1 += p0[lane + 64];
            a2 += p0[lane + 128];
        }
    }
    red[wave][lane] = a0;
    red[wave][lane + 64] = a1;
    red[wave][lane + 128] = a2;
    __syncthreads();
    if (t < 192) {
        const float sum = red[0][t] + red[1][t] + red[2][t] + red[3][t];
        sentF[b * 2304 + si * 768 + col0 + t] = sum * (1.0f / (float)n);
    }
}

// ---------------------------------------------------------------------------
// GEMM core (champion, verbatim): out(64 x Nout) += x(64 x K) @ B^T, 64x64
// tile, K-chunk [k0,k0+256). x always fp32 (workspace). Weights via `bf`.
// XMODE 0: x raw. XMODE 1: x = tanh(raw + bias[k % 768]).
// WMODE 0: W is [k][n] row-major, n-dim 768 (gc1_w/gc2_w).
// WMODE 1: conv weights (O=768, I=768, 3): B[n][k=kb*768+i] = W[n*2304+i*3+kb].
// mfma_f32_16x16x32_bf16; A[m=lane&15][k=quad*8+j]; B same; C/D col=lane&15,
// row=quad*4+reg.
// ---------------------------------------------------------------------------
template <int XMODE, int WMODE>
__device__ __forceinline__ void gemm_core(
    const float* __restrict__ x, int xstride, const void* __restrict__ bias,
    const void* __restrict__ W, bool bf,
    float* __restrict__ out, int ostride,
    int n0, int k0, u16* As, u16* Bs)
{
    const int t = threadIdx.x;
    const int r = t >> 2;             // 0..63
    const int cseg = (t & 3) * 32;    // 0,32,64,96
    const int wave = t >> 6, lane = t & 63;
    const int lm = lane & 15, lq = lane >> 4;
    f32x4 acc[4] = {};

    for (int kk = 0; kk < 256; kk += 128) {
        const int kg = k0 + kk;
        // ---- stage x -> As (fp32 -> bf16), row stride 136 ----
        {
            const float* xp = x + (size_t)r * xstride + (kg + cseg);
            u16* dst = As + r * 136 + cseg;
#pragma unroll
            for (int i = 0; i < 8; ++i) {
                float4 v = ((const float4*)xp)[i];
                if (XMODE == 1) {
                    int kb = kg + cseg + i * 4;
                    if (kb >= 768) kb -= 768;   // K <= 1536, 4-aligned
                    v.x = tanhf(v.x + ldv(bias, kb, bf));
                    v.y = tanhf(v.y + ldv(bias, kb + 1, bf));
                    v.z = tanhf(v.z + ldv(bias, kb + 2, bf));
                    v.w = tanhf(v.w + ldv(bias, kb + 3, bf));
                }
                ((ushort4*)dst)[i] = make_ushort4(f2bf(v.x), f2bf(v.y), f2bf(v.z), f2bf(v.w));
            }
        }
        // ---- stage W -> Bs as [n][k], row stride 136 ----
        if (WMODE == 0) {
            const int p = t >> 2;             // k-pair: k = 2p, 2p+1
            const int nseg = (t & 3) * 16;    // 16 n's
            u16 q0[16], q1[16];
            if (bf) {
                const u16* w0 = (const u16*)W + (size_t)(kg + 2 * p) * 768 + n0 + nseg;
                ((uint4*)q0)[0] = ((const uint4*)w0)[0];
                ((uint4*)q0)[1] = ((const uint4*)w0)[1];
                ((uint4*)q1)[0] = ((const uint4*)(w0 + 768))[0];
                ((uint4*)q1)[1] = ((const uint4*)(w0 + 768))[1];
            } else {
                const float* w0 = (const float*)W + (size_t)(kg + 2 * p) * 768 + n0 + nseg;
#pragma unroll
                for (int e = 0; e < 4; ++e) {
                    float4 v0 = ((const float4*)w0)[e];
                    float4 v1 = ((const float4*)(w0 + 768))[e];
                    q0[4 * e] = f2bf(v0.x); q0[4 * e + 1] = f2bf(v0.y);
                    q0[4 * e + 2] = f2bf(v0.z); q0[4 * e + 3] = f2bf(v0.w);
                    q1[4 * e] = f2bf(v1.x); q1[4 * e + 1] = f2bf(v1.y);
                    q1[4 * e + 2] = f2bf(v1.z); q1[4 * e + 3] = f2bf(v1.w);
                }
            }
#pragma unroll
            for (int e = 0; e < 16; ++e)
                *(ushort2*)(Bs + (nseg + e) * 136 + 2 * p) = make_ushort2(q0[e], q1[e]);
        } else {
            // conv: within a 128-chunk, kb = kg/768 is constant (768 = 6*128)
            const int kb = kg / 768;
            const int i0c = kg - kb * 768;
            u16 tmp[32];
            if (bf) {
                const u16* wp = (const u16*)W + (size_t)(n0 + r) * 2304 + (size_t)(i0c + cseg) * 3 + kb;
#pragma unroll
                for (int j = 0; j < 32; ++j) tmp[j] = wp[j * 3];
            } else {
                const float* wp = (const float*)W + (size_t)(n0 + r) * 2304 + (size_t)(i0c + cseg) * 3 + kb;
#pragma unroll
                for (int j = 0; j < 32; ++j) tmp[j] = f2bf(wp[j * 3]);
            }
            u16* dst = Bs + r * 136 + cseg;
#pragma unroll
            for (int qq = 0; qq < 8; ++qq)
                ((ushort4*)dst)[qq] = ((ushort4*)tmp)[qq];
        }
        __syncthreads();
        const u16* ap = As + (wave * 16 + lm) * 136 + lq * 8;
        const u16* bp = Bs + lm * 136 + lq * 8;
#pragma unroll
        for (int ks = 0; ks < 4; ++ks) {
            short8 af = *(const short8*)(ap + ks * 32);
#pragma unroll
            for (int nf = 0; nf < 4; ++nf) {
                short8 bfr = *(const short8*)(bp + nf * 16 * 136 + ks * 32);
                acc[nf] = __builtin_amdgcn_mfma_f32_16x16x32_bf16(af, bfr, acc[nf], 0, 0, 0);
            }
        }
        __syncthreads();
    }
#pragma unroll
    for (int nf = 0; nf < 4; ++nf) {
#pragma unroll
        for (int rg = 0; rg < 4; ++rg) {
            const int row = wave * 16 + lq * 4 + rg;
            const int col = n0 + nf * 16 + lm;
            atomicAdd(out + (size_t)row * ostride + col, acc[nf][rg]);
        }
    }
}

// Stage A: g1pre = sent7 @ gc1_w (K=768); c1_6 (K=2304, x=[s5|s6|s7]); c1_7 (K=1536, x=[s6|s7])
__global__ __launch_bounds__(256) void k2_gemm_a(
    const float* __restrict__ sentF, const void* __restrict__ gc1w,
    const void* __restrict__ c1w, float* __restrict__ g1acc, float* __restrict__ c1acc,
    const float* __restrict__ flagp)
{
    __shared__ u16 As[64 * 136];
    __shared__ u16 Bs[64 * 136];
    const bool bf = flagp[0] > 0.5f;
    const int u = blockIdx.x;
    if (u < 36) {
        gemm_core<0, 0>(sentF + 1536, 2304, nullptr, gc1w, bf, g1acc, 768,
                        (u / 3) * 64, (u % 3) * 256, As, Bs);
    } else if (u < 144) {
        const int v = u - 36;
        gemm_core<0, 1>(sentF, 2304, nullptr, c1w, bf, c1acc, 1536,
                        (v / 9) * 64, (v % 9) * 256, As, Bs);
    } else {
        const int v = u - 144;
        gemm_core<0, 1>(sentF + 768, 2304, nullptr, c1w, bf, c1acc + 768, 1536,
                        (v / 6) * 64, (v % 6) * 256, As, Bs);
    }
}

// Stage B: g2pre = tanh(g1+gc1_b) @ gc2_w (K=768); c2pre = tanh(c1+c1b) @ W2 (K=1536)
__global__ __launch_bounds__(256) void k3_gemm_b(
    const float* __restrict__ g1acc, const float* __restrict__ c1acc,
    const void* __restrict__ gc2w, const void* __restrict__ c2w,
    const void* __restrict__ gc1b, const void* __restrict__ c1b,
    float* __restrict__ g2acc, float* __restrict__ c2acc,
    const float* __restrict__ flagp)
{
    __shared__ u16 As[64 * 136];
    __shared__ u16 Bs[64 * 136];
    const bool bf = flagp[0] > 0.5f;
    const int u = blockIdx.x;
    if (u < 36) {
        gemm_core<1, 0>(g1acc, 768, gc1b, gc2w, bf, g2acc, 768,
                        (u / 3) * 64, (u % 3) * 256, As, Bs);
    } else {
        const int v = u - 36;
        gemm_core<1, 1>(c1acc, 1536, c1b, c2w, bf, c2acc, 768,
                        (v / 6) * 64, (v % 6) * 256, As, Bs);
    }
}

// ---------------------------------------------------------------------------
// k4: per-batch refine chains + softmax + fc2 (champion, verbatim)
// ---------------------------------------------------------------------------
__device__ __forceinline__ float block_sum(float v, float* red) {
#pragma unroll
    for (int m = 1; m < 64; m <<= 1) v += __shfl_xor(v, m, 64);
    const int wave = threadIdx.x >> 6, lane = threadIdx.x & 63;
    if (lane == 0) red[wave] = v;
    __syncthreads();
    const float r = red[0] + red[1] + red[2] + red[3];
    __syncthreads();
    return r;
}

__global__ __launch_bounds__(256) void k4_final(
    const float* __restrict__ sentF, const float* __restrict__ g2acc,
    const float* __restrict__ c2acc,
    const void* __restrict__ gc2b, const void* __restrict__ c2b,
    const void* __restrict__ lng, const void* __restrict__ lnb,
    const void* __restrict__ target, const void* __restrict__ fc2w,
    const void* __restrict__ fc2b, void* __restrict__ outp,
    const float* __restrict__ flagp)
{
    __shared__ float red[4];
    const bool bf = flagp[0] > 0.5f;
    const int t = threadIdx.x, b = blockIdx.x;
    float s_[3], g_[3], bb_[3];
    const float* srow = sentF + b * 2304 + 1536;  // sent7
#pragma unroll
    for (int i = 0; i < 3; ++i) {
        const int d = t + 256 * i;
        s_[i] = srow[d];
        g_[i] = ldv(lng, d, bf);
        bb_[i] = ldv(lnb, d, bf);
    }

    auto refine2 = [&](float* yv) {
#pragma unroll
        for (int it = 0; it < 2; ++it) {
            const float c = block_sum(yv[0] * s_[0] + yv[1] * s_[1] + yv[2] * s_[2], red);
            float tt[3], sm = 0.0f, sq = 0.0f;
#pragma unroll
            for (int i = 0; i < 3; ++i) {
                tt[i] = sigm(c * s_[i]);
                sm += tt[i];
                sq += tt[i] * tt[i];
            }
            const float m = block_sum(sm, red) * (1.0f / 768.0f);
            const float q = block_sum(sq, red) * (1.0f / 768.0f);
            const float inv = rsqrtf(fmaxf(q - m * m, 0.0f) + 1e-5f);
#pragma unroll
            for (int i = 0; i < 3; ++i)
                yv[i] = 0.5f * ((tt[i] - m) * inv * g_[i] + bb_[i]) + s_[i];
        }
    };

    float a3[3], a4[3], a5[3], y[3];
#pragma unroll
    for (int i = 0; i < 3; ++i) {
        const int d = t + 256 * i;
        y[i] = tanhf(g2acc[b * 768 + d] + ldv(gc2b, d, bf));
    }
    refine2(y);
    a3[0] = y[0]; a3[1] = y[1]; a3[2] = y[2];
#pragma unroll
    for (int i = 0; i < 3; ++i) {
        const int d = t + 256 * i;
        y[i] = tanhf(c2acc[b * 768 + d] + ldv(c2b, d, bf));
    }
    refine2(y);
    a4[0] = y[0]; a4[1] = y[1]; a4[2] = y[2];
    const float ss = block_sum(s_[0] * s_[0] + s_[1] * s_[1] + s_[2] * s_[2], red);
#pragma unroll
    for (int i = 0; i < 3; ++i) y[i] = sigm(ss * s_[i]);
    refine2(y);
    a5[0] = y[0]; a5[1] = y[1]; a5[2] = y[2];

    float tg[3];
#pragma unroll
    for (int i = 0; i < 3; ++i) tg[i] = ldv(target, t + 256 * i, bf);  // target[0]
    const float u0 = block_sum(a3[0] * tg[0] + a3[1] * tg[1] + a3[2] * tg[2], red);
    const float u1 = block_sum(a4[0] * tg[0] + a4[1] * tg[1] + a4[2] * tg[2], red);
    const float u2 = block_sum(a5[0] * tg[0] + a5[1] * tg[1] + a5[2] * tg[2], red);
    const float mx = fmaxf(u0, fmaxf(u1, u2));
    const float e0 = __expf(u0 - mx), e1 = __expf(u1 - mx), e2 = __expf(u2 - mx);
    const float es = e0 + e1 + e2;
    const float w0 = e0 / es, w1 = e1 / es, w2 = e2 / es;

    float p0 = 0.0f, p1 = 0.0f, p2 = 0.0f;
#pragma unroll
    for (int i = 0; i < 3; ++i) {
        const int d = t + 256 * i;
        const float va = w0 * a3[i], vb = w1 * a4[i], vc = w2 * a5[i];
        p0 += va * ldv(fc2w, d * 3 + 0, bf) + vb * ldv(fc2w, (768 + d) * 3 + 0, bf) + vc * ldv(fc2w, (1536 + d) * 3 + 0, bf);
        p1 += va * ldv(fc2w, d * 3 + 1, bf) + vb * ldv(fc2w, (768 + d) * 3 + 1, bf) + vc * ldv(fc2w, (1536 + d) * 3 + 1, bf);
        p2 += va * ldv(fc2w, d * 3 + 2, bf) + vb * ldv(fc2w, (768 + d) * 3 + 2, bf) + vc * ldv(fc2w, (1536 + d) * 3 + 2, bf);
    }
    p0 = block_sum(p0, red);
    p1 = block_sum(p1, red);
    p2 = block_sum(p2, red);
    if (t == 0) {
        const float o0 = p0 + ldv(fc2b, 0, bf);
        const float o1 = p1 + ldv(fc2b, 1, bf);
        const float o2 = p2 + ldv(fc2b, 2, bf);
        if (bf) {
            ((u16*)outp)[b * 3 + 0] = f2bf(o0);
            ((u16*)outp)[b * 3 + 1] = f2bf(o1);
            ((u16*)outp)[b * 3 + 2] = f2bf(o2);
        } else {
            ((float*)outp)[b * 3 + 0] = o0;
            ((float*)outp)[b * 3 + 1] = o1;
            ((float*)outp)[b * 3 + 2] = o2;
        }
    }
}

extern "C" void kernel_launch(void* const* d_in, const int* in_sizes, int n_in,
                              void* d_out, int out_size, void* d_ws, size_t ws_size,
                              hipStream_t stream) {
    const void* bert   = d_in[0];
    const void* target = d_in[1];
    const void* gc1w   = d_in[2];
    const void* gc1b   = d_in[3];
    const void* gc2w   = d_in[4];
    const void* gc2b   = d_in[5];
    const void* c1w    = d_in[6];
    const void* c1b    = d_in[7];
    const void* c2w    = d_in[8];
    const void* c2b    = d_in[9];
    const void* lng    = d_in[10];
    const void* lnb    = d_in[11];
    const void* fc2w   = d_in[12];
    const void* fc2b   = d_in[13];
    const int*  sb     = (const int*)d_in[14];

    float* sentF = (float*)d_ws;       // 147456 floats
    float* accs  = sentF + 147456;     // 245760 floats
    float* g1acc = accs;               // 64 x 768
    float* c1acc = accs + 49152;       // 64 x 1536  [c1_6 | c1_7]
    float* g2acc = c1acc + 98304;      // 64 x 768
    float* c2acc = g2acc + 49152;      // 64 x 768
    float* flagp = accs + 245760;      // 1 float (dtype flag)

    kA_pool<<<768, 256, 0, stream>>>(bert, sb, sentF, accs, flagp);
    k2_gemm_a<<<216, 256, 0, stream>>>(sentF, gc1w, c1w, g1acc, c1acc, flagp);
    k3_gemm_b<<<108, 256, 0, stream>>>(g1acc, c1acc, gc2w, c2w, gc1b, c1b, g2acc, c2acc, flagp);
    k4_final<<<64, 256, 0, stream>>>(sentF, g2acc, c2acc, gc2b, c2b, lng, lnb,
                                     target, fc2w, fc2b, d_out, flagp);
}